// Round 1
// 445.886 us; speedup vs baseline: 1.0392x; 1.0392x over previous
//
#include <hip/hip_runtime.h>
#include <math.h>

#define NB 4
#define SEQ 4096
#define DM 1024
#define NG 4
#define DI 512
#define NQS 1024
#define NKS 512
#define NHD 8
#define DHD 64
#define VTS 520  // vtbuf row stride (512 cols used, padded)

typedef unsigned int u32;
typedef unsigned short u16;
typedef __bf16 bf16x8 __attribute__((ext_vector_type(8)));
typedef float f32x4 __attribute__((ext_vector_type(4)));

__device__ __forceinline__ float bf2f(u16 u) { return __uint_as_float(((u32)u) << 16); }
__device__ __forceinline__ u16 f2bf(float f) {
  u32 u = __float_as_uint(f);
  u32 r = (u + 0x7FFFu + ((u >> 16) & 1u)) >> 16;
  return (u16)r;
}
// hardware RNE bf16 convert (compiler pairs into v_cvt_pk_bf16_f32)
__device__ __forceinline__ u16 f2bfh(float f) {
  union { __bf16 b; u16 u; } cv;
  cv.b = (__bf16)f;
  return cv.u;
}

// ---------------- fp32 -> bf16 bulk convert ----------------
__global__ __launch_bounds__(256) void convert_bf16(const float* __restrict__ src,
                                                    u16* __restrict__ dst, int n4) {
  int i = blockIdx.x * 256 + threadIdx.x;
  if (i < n4) {
    float4 v = ((const float4*)src)[i];
    ushort4 o;
    o.x = f2bf(v.x); o.y = f2bf(v.y); o.z = f2bf(v.z); o.w = f2bf(v.w);
    ((ushort4*)dst)[i] = o;
  }
}

// ---------------- router: logits[b][g][n] for q and kv (fp32 — selection exactness) ----------------
__global__ __launch_bounds__(256) void router_kernel(
    const float* __restrict__ x, const float* __restrict__ wqr,
    const float* __restrict__ wkvr, float* __restrict__ qlog,
    float* __restrict__ kvlog) {
  __shared__ float wsm[8192];
  int tid = threadIdx.x;
  for (int k = tid; k < 8192; k += 256)
    wsm[k] = (k < 4096) ? wqr[k] : wkvr[k - 4096];
  __syncthreads();
  int widx = blockIdx.x * 4 + (tid >> 6);
  int lane = tid & 63;
  int b = widx >> 12, tok = widx & 4095;
  const float4* xr = (const float4*)(x + ((size_t)(b * SEQ + tok)) * DM);
  float4 xv[4];
#pragma unroll
  for (int i = 0; i < 4; i++) xv[i] = xr[i * 64 + lane];
  float accs[8];
#pragma unroll
  for (int r = 0; r < 8; r++) {
    const float4* wr = (const float4*)(wsm + r * 1024);
    float a = 0.f;
#pragma unroll
    for (int i = 0; i < 4; i++) {
      float4 w4 = wr[i * 64 + lane];
      a += xv[i].x * w4.x + xv[i].y * w4.y + xv[i].z * w4.z + xv[i].w * w4.w;
    }
    accs[r] = a;
  }
#pragma unroll
  for (int r = 0; r < 8; r++) {
    float a = accs[r];
#pragma unroll
    for (int off = 32; off >= 1; off >>= 1) a += __shfl_xor(a, off);
    if (lane == 0) {
      if (r < 4) qlog[((b << 2) | r) * SEQ + tok] = a;
      else kvlog[((b << 2) | (r - 4)) * SEQ + tok] = a;
    }
  }
}

// ---------------- top-k radix select per (b,g) ----------------
__global__ __launch_bounds__(256) void topk_kernel(
    const float* __restrict__ logits, int K, int* __restrict__ out_idx,
    float* __restrict__ out_score, float* __restrict__ counts) {
  __shared__ u32 keys[4096];
  __shared__ int eqlist[2048];
  __shared__ int scnt[4];
  __shared__ int s_gt, s_eq;
  int bg = blockIdx.x;
  int tid = threadIdx.x;
  const float* L = logits + bg * 4096;
  for (int e = tid; e < 4096; e += 256) {
    u32 u = __float_as_uint(L[e]);
    keys[e] = (u >> 31) ? ~u : (u | 0x80000000u);
  }
  if (tid == 0) { s_gt = 0; s_eq = 0; }
  __syncthreads();
  u32 prefix = 0;
  int remaining = K;
  for (int bit = 31; bit >= 0; --bit) {
    u32 want = prefix | (1u << bit);
    u32 mask = ~((1u << bit) - 1u);
    int c = 0;
    for (int e = tid; e < 4096; e += 256) c += ((keys[e] & mask) == want) ? 1 : 0;
#pragma unroll
    for (int off = 32; off >= 1; off >>= 1) c += __shfl_xor(c, off);
    if ((tid & 63) == 0) scnt[tid >> 6] = c;
    __syncthreads();
    int total = scnt[0] + scnt[1] + scnt[2] + scnt[3];
    if (total >= remaining) prefix = want;
    else remaining -= total;
    __syncthreads();
  }
  u32 T = prefix;
  for (int e = tid; e < 4096; e += 256) {
    u32 k = keys[e];
    if (k > T) {
      int pos = atomicAdd(&s_gt, 1);
      out_idx[bg * K + pos] = e;
      float v = L[e];
      out_score[bg * K + pos] = 1.0f / (1.0f + __expf(-v));
      if (counts) atomicAdd(&counts[(bg >> 2) * SEQ + e], 1.0f);
    } else if (k == T) {
      int p = atomicAdd(&s_eq, 1);
      if (p < 2048) eqlist[p] = e;
    }
  }
  __syncthreads();
  int gt = s_gt;
  int eq = min(s_eq, 2048);
  int need = K - gt;
  for (int i = tid; i < eq; i += 256) {
    int my = eqlist[i];
    int rank = 0;
    for (int j = 0; j < eq; j++) rank += (eqlist[j] < my) ? 1 : 0;
    if (rank < need) {
      int pos = gt + rank;
      out_idx[bg * K + pos] = my;
      float v = L[my];
      out_score[bg * K + pos] = 1.0f / (1.0f + __expf(-v));
      if (counts) atomicAdd(&counts[(bg >> 2) * SEQ + my], 1.0f);
    }
  }
}

// ---------------- shared MFMA GEMM core: 128x128 tile, BK=64, swizzled LDS ----------------
struct Ptr4 { const u16* p[4]; };

__device__ __forceinline__ void mfma_core(Ptr4 A, Ptr4 B, u16* Asm, u16* Bsm,
                                          int ktiles, int tid, f32x4 (&acc)[4][4]) {
  int w = tid >> 6, lane = tid & 63;
  int col = lane & 15, quad = lane >> 4;
  int wr = w >> 1, wc = w & 1;
  for (int kt = 0; kt < ktiles; kt++) {
#pragma unroll
    for (int r = 0; r < 4; r++) {
      char* ldsA = (char*)Asm + (r * 256 + w * 64) * 16;
      __builtin_amdgcn_global_load_lds(
          (const __attribute__((address_space(1))) void*)(A.p[r] + kt * 64),
          (__attribute__((address_space(3))) void*)ldsA, 16, 0, 0);
    }
#pragma unroll
    for (int r = 0; r < 4; r++) {
      char* ldsB = (char*)Bsm + (r * 256 + w * 64) * 16;
      __builtin_amdgcn_global_load_lds(
          (const __attribute__((address_space(1))) void*)(B.p[r] + kt * 64),
          (__attribute__((address_space(3))) void*)ldsB, 16, 0, 0);
    }
    __syncthreads();
#pragma unroll
    for (int k04 = 0; k04 < 8; k04 += 4) {
      bf16x8 af[4], bfr[4];
#pragma unroll
      for (int t = 0; t < 4; t++) {
        int rowa = wr * 64 + t * 16 + col;
        int sp = (quad + k04) ^ (col & 7);
        af[t] = *(const bf16x8*)((const char*)Asm + (rowa * 8 + sp) * 16);
        int rowb = wc * 64 + t * 16 + col;
        bfr[t] = *(const bf16x8*)((const char*)Bsm + (rowb * 8 + sp) * 16);
      }
#pragma unroll
      for (int t = 0; t < 4; t++)
#pragma unroll
        for (int u = 0; u < 4; u++)
          acc[t][u] = __builtin_amdgcn_mfma_f32_16x16x32_bf16(af[t], bfr[u], acc[t][u], 0, 0, 0);
    }
    __syncthreads();
  }
}

// ---------------- q projection: qbuf[bg][1024][512] = gather(xbf) @ wq^T, pre-scaled by DH^-0.5 ----------------
__global__ __launch_bounds__(256) void gemm_qproj(
    const u16* __restrict__ xbf, const int* __restrict__ qidx,
    const u16* __restrict__ wqbf, u16* __restrict__ qbuf) {
  int bg = blockIdx.z, b = bg >> 2, g = bg & 3;
  int row0 = blockIdx.y * 128, col0 = blockIdx.x * 128;
  __shared__ __align__(16) u16 Asm[8192], Bsm[8192];
  __shared__ int ridx[128];
  int tid = threadIdx.x;
  if (tid < 128) ridx[tid] = qidx[bg * NQS + row0 + tid];
  __syncthreads();
  Ptr4 A, B;
#pragma unroll
  for (int r = 0; r < 4; r++) {
    int G = r * 256 + tid;
    int row = G >> 3;
    int seg = (G & 7) ^ (row & 7);
    A.p[r] = xbf + ((size_t)b * SEQ + ridx[row]) * DM + seg * 8;
    B.p[r] = wqbf + ((size_t)g * DI + col0 + row) * DM + seg * 8;
  }
  f32x4 acc[4][4] = {};
  mfma_core(A, B, Asm, Bsm, DM / 64, tid, acc);
  int w = tid >> 6, lane = tid & 63;
  int col = lane & 15, quad = lane >> 4;
  int wr = w >> 1, wc = w & 1;
#pragma unroll
  for (int t = 0; t < 4; t++)
#pragma unroll
    for (int u = 0; u < 4; u++)
#pragma unroll
      for (int r = 0; r < 4; r++) {
        int rowg = row0 + wr * 64 + t * 16 + quad * 4 + r;
        int colg = col0 + wc * 64 + u * 16 + col;
        // pre-scale q by DH^-0.5 = 0.125 (power of two: exact in bf16)
        qbuf[((size_t)bg * NQS + rowg) * DI + colg] = f2bf(acc[t][u][r] * 0.125f);
      }
}

// ---------------- kv projection: K -> kbuf, V^T (scaled) -> vtbuf ----------------
__global__ __launch_bounds__(256) void gemm_kvproj(
    const u16* __restrict__ xbf, const int* __restrict__ kvidx,
    const u16* __restrict__ wkvbf, const float* __restrict__ kvscore,
    u16* __restrict__ kbuf, u16* __restrict__ vtbuf) {
  int bg = blockIdx.z, b = bg >> 2, g = bg & 3;
  int row0 = blockIdx.y * 128, col0 = blockIdx.x * 128;
  __shared__ __align__(16) u16 Asm[8192], Bsm[8192];
  __shared__ int ridx[128];
  int tid = threadIdx.x;
  if (tid < 128) ridx[tid] = kvidx[bg * NKS + row0 + tid];
  __syncthreads();
  Ptr4 A, B;
#pragma unroll
  for (int r = 0; r < 4; r++) {
    int G = r * 256 + tid;
    int row = G >> 3;
    int seg = (G & 7) ^ (row & 7);
    A.p[r] = xbf + ((size_t)b * SEQ + ridx[row]) * DM + seg * 8;
    B.p[r] = wkvbf + ((size_t)g * (2 * DI) + col0 + row) * DM + seg * 8;
  }
  f32x4 acc[4][4] = {};
  mfma_core(A, B, Asm, Bsm, DM / 64, tid, acc);
  int w = tid >> 6, lane = tid & 63;
  int col = lane & 15, quad = lane >> 4;
  int wr = w >> 1, wc = w & 1;
  if (col0 < DI) {
#pragma unroll
    for (int t = 0; t < 4; t++)
#pragma unroll
      for (int u = 0; u < 4; u++)
#pragma unroll
        for (int r = 0; r < 4; r++) {
          int rowg = row0 + wr * 64 + t * 16 + quad * 4 + r;
          int colg = col0 + wc * 64 + u * 16 + col;
          kbuf[((size_t)bg * NKS + rowg) * DI + colg] = f2bf(acc[t][u][r]);
        }
  } else {
#pragma unroll
    for (int t = 0; t < 4; t++)
#pragma unroll
      for (int r = 0; r < 4; r++) {
        int rowg = row0 + wr * 64 + t * 16 + quad * 4 + r;
        float sc = kvscore[bg * NKS + rowg];
#pragma unroll
        for (int u = 0; u < 4; u++) {
          int vc = col0 - DI + wc * 64 + u * 16 + col;  // 0..511
          int h = vc >> 6, d = vc & 63;
          // col index = rowg directly (null column handled analytically in attn)
          vtbuf[(((size_t)bg * NHD + h) * DHD + d) * VTS + rowg] =
              f2bf(acc[t][u][r] * sc);
        }
      }
  }
}

// ---------------- out projection + scaled scatter-add ----------------
__global__ __launch_bounds__(256) void gemm_outproj(
    const u16* __restrict__ obuf, const u16* __restrict__ woutbf,
    const int* __restrict__ qidx, const float* __restrict__ qscore,
    float* __restrict__ dout) {
  int bg = blockIdx.z, b = bg >> 2, g = bg & 3;
  int row0 = blockIdx.y * 128, col0 = blockIdx.x * 128;
  __shared__ __align__(16) u16 Asm[8192], Bsm[8192];
  int tid = threadIdx.x;
  Ptr4 A, B;
#pragma unroll
  for (int r = 0; r < 4; r++) {
    int G = r * 256 + tid;
    int row = G >> 3;
    int seg = (G & 7) ^ (row & 7);
    A.p[r] = obuf + ((size_t)bg * NQS + row0 + row) * DI + seg * 8;
    B.p[r] = woutbf + ((size_t)g * DM + col0 + row) * DI + seg * 8;
  }
  f32x4 acc[4][4] = {};
  mfma_core(A, B, Asm, Bsm, DI / 64, tid, acc);
  int w = tid >> 6, lane = tid & 63;
  int col = lane & 15, quad = lane >> 4;
  int wr = w >> 1, wc = w & 1;
#pragma unroll
  for (int t = 0; t < 4; t++)
#pragma unroll
    for (int r = 0; r < 4; r++) {
      int rowg = row0 + wr * 64 + t * 16 + quad * 4 + r;
      float sc = qscore[bg * NQS + rowg];
      int tok = qidx[bg * NQS + rowg];
      float* orow = dout + ((size_t)b * SEQ + tok) * DM;
#pragma unroll
      for (int u = 0; u < 4; u++) {
        int colg = col0 + wc * 64 + u * 16 + col;
        atomicAdd(&orow[colg], acc[t][u][r] * sc);
      }
    }
}

// ---------------- MFMA flash attention v3 ----------------
// KVBLK=64 (8 uniform tiles over the 512 real KV rows), null column handled
// analytically in the prologue (m0 = q.k_null, l0 = 1, oacc0 = v_null — exact
// online-softmax init). T14 issue-early/write-late staging: next tile's global
// loads are issued into registers before the barrier and written to LDS at the
// top of the next iteration, so HBM/L2 latency hides under a full tile of
// compute. LDS = 27.6 KB -> 5 blocks/CU (vs 53 KB -> 3). Deferred l-reduction
// (per-lane partials, one cross-lane reduce at the end). q arrives pre-scaled
// by DH^-0.5 from gemm_qproj, so no per-element mask/scale VALU anywhere.
__global__ __launch_bounds__(256, 4) void attn_mfma(
    const u16* __restrict__ qbuf, const u16* __restrict__ kbuf,
    const u16* __restrict__ vtbuf, const float* __restrict__ null_kv,
    u16* __restrict__ obuf) {
  int qt = blockIdx.x;
  int h = blockIdx.y;
  int bg = blockIdx.z;
  int g = bg & 3;
  int tid = threadIdx.x;
  int w = tid >> 6, lane = tid & 63;
  int col = lane & 15, quad = lane >> 4;

  __shared__ __align__(16) u16 Ks[64][72];
  __shared__ __align__(16) u16 Vts[64][72];
  __shared__ __align__(16) u16 Ps[4][16][72];

  int q0 = qt * 64 + w * 16;
  const u16* qp = qbuf + ((size_t)bg * NQS + q0 + col) * DI + h * DHD + quad * 8;
  bf16x8 qa0 = *(const bf16x8*)qp;
  bf16x8 qa1 = *(const bf16x8*)(qp + 32);

  // --- null-column prologue: exact online-softmax init ---
  const float* kn = null_kv + ((size_t)(0 * NG + g) * NHD + h) * DHD;
  const float* vn = null_kv + ((size_t)(1 * NG + g) * NHD + h) * DHD;
  float sn = 0.f;
#pragma unroll
  for (int i = 0; i < 8; i++) {
    sn += (float)qa0[i] * kn[quad * 8 + i];
    sn += (float)qa1[i] * kn[32 + quad * 8 + i];
  }
  // q is pre-scaled by 0.125, so sn is already in score units.
  // sn is the partial for q-row = col over this lane's k-slice; sum the 4 quads.
  sn += __shfl_xor(sn, 16);
  sn += __shfl_xor(sn, 32);
  float m_run[4], l_lane[4];
  f32x4 oacc[4];
#pragma unroll
  for (int r = 0; r < 4; r++) {
    m_run[r] = __shfl(sn, quad * 4 + r);   // s_null for C-layout row quad*4+r
    l_lane[r] = (col == 0) ? 1.f : 0.f;    // null's p = exp(0) = 1, seeded once
  }
#pragma unroll
  for (int t = 0; t < 4; t++) {
    float v = vn[t * 16 + col];            // oacc0 = 1 * v_null (same for all rows)
    f32x4 tmp = {v, v, v, v};
    oacc[t] = tmp;
  }

  // --- staging setup: 64x64 K tile + 64x64 V^T tile, 32B per thread each ---
  int sr = tid >> 2, ss = tid & 3;
  const u16* kptr = kbuf + ((size_t)bg * NKS + sr) * DI + h * DHD + ss * 16;
  const u16* vptr = vtbuf + (((size_t)bg * NHD + h) * DHD + sr) * VTS + ss * 16;
  uint4* kdst = (uint4*)&Ks[sr][ss * 16];
  uint4* vdst = (uint4*)&Vts[sr][ss * 16];
  uint4 ck0, ck1, cv0, cv1;
  { const uint4* p = (const uint4*)kptr; ck0 = p[0]; ck1 = p[1]; }
  { const uint4* p = (const uint4*)vptr; cv0 = p[0]; cv1 = p[1]; }

  for (int c = 0; c < 8; ++c) {
    // write-late: regs (loaded last iteration) -> LDS
    kdst[0] = ck0; kdst[1] = ck1;
    vdst[0] = cv0; vdst[1] = cv1;
    // issue-early: next tile's global loads, in flight across the barrier
    uint4 nk0, nk1, nv0, nv1;
    bool pf = (c < 7);
    if (pf) {
      const uint4* p = (const uint4*)(kptr + (size_t)(c + 1) * 64 * DI);
      nk0 = p[0]; nk1 = p[1];
      const uint4* q4 = (const uint4*)(vptr + (c + 1) * 64);
      nv0 = q4[0]; nv1 = q4[1];
    }
    __syncthreads();

    // QK^T for this 64-col tile (no masks: all 512 rows are real)
    f32x4 sv[4];
#pragma unroll
    for (int t = 0; t < 4; t++) {
      bf16x8 kb0 = *(const bf16x8*)&Ks[t * 16 + col][quad * 8];
      bf16x8 kb1 = *(const bf16x8*)&Ks[t * 16 + col][quad * 8 + 32];
      f32x4 s = {0.f, 0.f, 0.f, 0.f};
      s = __builtin_amdgcn_mfma_f32_16x16x32_bf16(qa0, kb0, s, 0, 0, 0);
      s = __builtin_amdgcn_mfma_f32_16x16x32_bf16(qa1, kb1, s, 0, 0, 0);
      sv[t] = s;
    }
    float alpha[4];
#pragma unroll
    for (int r = 0; r < 4; r++) {
      float m = fmaxf(fmaxf(sv[0][r], sv[1][r]), fmaxf(sv[2][r], sv[3][r]));
      m = fmaxf(m, __shfl_xor(m, 1));
      m = fmaxf(m, __shfl_xor(m, 2));
      m = fmaxf(m, __shfl_xor(m, 4));
      m = fmaxf(m, __shfl_xor(m, 8));
      float mnew = fmaxf(m_run[r], m);
      alpha[r] = __expf(m_run[r] - mnew);
      m_run[r] = mnew;
    }
    float rs[4] = {0.f, 0.f, 0.f, 0.f};
#pragma unroll
    for (int t = 0; t < 4; t++)
#pragma unroll
      for (int r = 0; r < 4; r++) {
        float p = __expf(sv[t][r] - m_run[r]);
        rs[r] += p;
        Ps[w][quad * 4 + r][t * 16 + col] = f2bfh(p);
      }
#pragma unroll
    for (int r = 0; r < 4; r++) l_lane[r] = l_lane[r] * alpha[r] + rs[r];
#pragma unroll
    for (int t = 0; t < 4; t++)
#pragma unroll
      for (int r = 0; r < 4; r++) oacc[t][r] *= alpha[r];

    // PV (Ps write->read is same-wave; LDS is in-order per wave)
#pragma unroll
    for (int s2 = 0; s2 < 2; s2++) {
      bf16x8 pa = *(const bf16x8*)&Ps[w][col][s2 * 32 + quad * 8];
#pragma unroll
      for (int t = 0; t < 4; t++) {
        bf16x8 vb = *(const bf16x8*)&Vts[t * 16 + col][s2 * 32 + quad * 8];
        oacc[t] = __builtin_amdgcn_mfma_f32_16x16x32_bf16(pa, vb, oacc[t], 0, 0, 0);
      }
    }
    __syncthreads();
    if (pf) { ck0 = nk0; ck1 = nk1; cv0 = nv0; cv1 = nv1; }
  }

  // deferred l reduction: one cross-lane pass for the whole kernel
  float inv[4];
#pragma unroll
  for (int r = 0; r < 4; r++) {
    float l = l_lane[r];
    l += __shfl_xor(l, 1);
    l += __shfl_xor(l, 2);
    l += __shfl_xor(l, 4);
    l += __shfl_xor(l, 8);
    inv[r] = 1.0f / l;
  }
#pragma unroll
  for (int t = 0; t < 4; t++) {
#pragma unroll
    for (int r = 0; r < 4; r++) {
      obuf[((size_t)bg * NQS + q0 + quad * 4 + r) * DI + h * DHD + t * 16 + col] =
          f2bfh(oacc[t][r] * inv[r]);
    }
  }
}

// ---------------- finalize: mean + null-token fill ----------------
__global__ __launch_bounds__(256) void finalize_kernel(
    float* __restrict__ dout, const float* __restrict__ counts,
    const float* __restrict__ null_token) {
  int qd = blockIdx.x * 256 + threadIdx.x;
  int row = qd >> 8;
  int c4 = qd & 255;
  float cnt = counts[row];
  float4* p = (float4*)dout + qd;
  if (cnt > 0.f) {
    float4 v = *p;
    float inv = 1.0f / cnt;
    v.x *= inv; v.y *= inv; v.z *= inv; v.w *= inv;
    *p = v;
  } else {
    *p = ((const float4*)null_token)[c4];
  }
}

extern "C" void kernel_launch(void* const* d_in, const int* in_sizes, int n_in,
                              void* d_out, int out_size, void* d_ws, size_t ws_size,
                              hipStream_t stream) {
  const float* x = (const float*)d_in[0];
  const float* wqr = (const float*)d_in[1];
  const float* wkvr = (const float*)d_in[2];
  const float* wq = (const float*)d_in[3];
  const float* wkv = (const float*)d_in[4];
  const float* wout = (const float*)d_in[5];
  const float* nullkv = (const float*)d_in[6];
  const float* nulltok = (const float*)d_in[7];
  float* out = (float*)d_out;
  char* ws = (char*)d_ws;
  // workspace layout (bytes)
  float* qlog = (float*)(ws + 0);                  // 256 KB
  float* kvlog = (float*)(ws + 262144);            // 256 KB
  int* qidx = (int*)(ws + 524288);                 // 64 KB
  int* kvidx = (int*)(ws + 589824);                // 32 KB
  float* qscore = (float*)(ws + 622592);           // 64 KB
  float* kvscore = (float*)(ws + 688128);          // 32 KB
  float* counts = (float*)(ws + 720896);           // 64 KB
  u16* qbuf = (u16*)(ws + 786432);                 // 16 MB  [16][1024][512]
  u16* kbuf = (u16*)(ws + 17563648);               // 8 MB   [16][512][512]
  u16* vtbuf = (u16*)(ws + 25952256);              // 8.13MB [16][8][64][520]
  u16* obuf = (u16*)(ws + 34476032);               // 16 MB  [16][1024][512]
  u16* xbf = (u16*)(ws + 51253248);                // 32 MB  [4][4096][1024]
  u16* wqbf = (u16*)(ws + 84807680);               // 4 MB   [4][512][1024]
  u16* wkvbf = (u16*)(ws + 89001984);              // 8 MB   [4][1024][1024]
  u16* woutbf = (u16*)(ws + 97390592);             // 4 MB   [4][1024][512]
  // total ~101.6 MB

  hipMemsetAsync(counts, 0, 65536, stream);
  hipMemsetAsync(out, 0, (size_t)NB * SEQ * DM * 4, stream);
  convert_bf16<<<16384, 256, 0, stream>>>(x, xbf, 4194304);
  convert_bf16<<<2048, 256, 0, stream>>>(wq, wqbf, 524288);
  convert_bf16<<<4096, 256, 0, stream>>>(wkv, wkvbf, 1048576);
  convert_bf16<<<2048, 256, 0, stream>>>(wout, woutbf, 524288);
  router_kernel<<<4096, 256, 0, stream>>>(x, wqr, wkvr, qlog, kvlog);
  topk_kernel<<<16, 256, 0, stream>>>(qlog, NQS, qidx, qscore, counts);
  topk_kernel<<<16, 256, 0, stream>>>(kvlog, NKS, kvidx, kvscore, nullptr);
  gemm_qproj<<<dim3(4, 8, 16), 256, 0, stream>>>(xbf, qidx, wqbf, qbuf);
  gemm_kvproj<<<dim3(8, 4, 16), 256, 0, stream>>>(xbf, kvidx, wkvbf, kvscore, kbuf, vtbuf);
  attn_mfma<<<dim3(16, 8, 16), 256, 0, stream>>>(qbuf, kbuf, vtbuf, nullkv, obuf);
  gemm_outproj<<<dim3(8, 8, 16), 256, 0, stream>>>(obuf, woutbf, qidx, qscore, out);
  finalize_kernel<<<16384, 256, 0, stream>>>(out, counts, nulltok);
}

// Round 2
// 404.944 us; speedup vs baseline: 1.1443x; 1.1011x over previous
//
#include <hip/hip_runtime.h>
#include <math.h>

#define NB 4
#define SEQ 4096
#define DM 1024
#define NG 4
#define DI 512
#define NQS 1024
#define NKS 512
#define NHD 8
#define DHD 64
#define VTS 520  // vtbuf row stride (512 cols used, padded)

typedef unsigned int u32;
typedef unsigned short u16;
typedef __bf16 bf16x8 __attribute__((ext_vector_type(8)));
typedef float f32x4 __attribute__((ext_vector_type(4)));

__device__ __forceinline__ float bf2f(u16 u) { return __uint_as_float(((u32)u) << 16); }
__device__ __forceinline__ u16 f2bf(float f) {
  u32 u = __float_as_uint(f);
  u32 r = (u + 0x7FFFu + ((u >> 16) & 1u)) >> 16;
  return (u16)r;
}
// hardware RNE bf16 convert (compiler pairs into v_cvt_pk_bf16_f32)
__device__ __forceinline__ u16 f2bfh(float f) {
  union { __bf16 b; u16 u; } cv;
  cv.b = (__bf16)f;
  return cv.u;
}

// ---------------- fp32 -> bf16 bulk convert ----------------
__global__ __launch_bounds__(256) void convert_bf16(const float* __restrict__ src,
                                                    u16* __restrict__ dst, int n4) {
  int i = blockIdx.x * 256 + threadIdx.x;
  if (i < n4) {
    float4 v = ((const float4*)src)[i];
    ushort4 o;
    o.x = f2bf(v.x); o.y = f2bf(v.y); o.z = f2bf(v.z); o.w = f2bf(v.w);
    ((ushort4*)dst)[i] = o;
  }
}

// ---------------- router: logits[b][g][n] for q and kv (fp32 — selection exactness) ----------------
__global__ __launch_bounds__(256) void router_kernel(
    const float* __restrict__ x, const float* __restrict__ wqr,
    const float* __restrict__ wkvr, float* __restrict__ qlog,
    float* __restrict__ kvlog) {
  __shared__ float wsm[8192];
  int tid = threadIdx.x;
  for (int k = tid; k < 8192; k += 256)
    wsm[k] = (k < 4096) ? wqr[k] : wkvr[k - 4096];
  __syncthreads();
  int widx = blockIdx.x * 4 + (tid >> 6);
  int lane = tid & 63;
  int b = widx >> 12, tok = widx & 4095;
  const float4* xr = (const float4*)(x + ((size_t)(b * SEQ + tok)) * DM);
  float4 xv[4];
#pragma unroll
  for (int i = 0; i < 4; i++) xv[i] = xr[i * 64 + lane];
  float accs[8];
#pragma unroll
  for (int r = 0; r < 8; r++) {
    const float4* wr = (const float4*)(wsm + r * 1024);
    float a = 0.f;
#pragma unroll
    for (int i = 0; i < 4; i++) {
      float4 w4 = wr[i * 64 + lane];
      a += xv[i].x * w4.x + xv[i].y * w4.y + xv[i].z * w4.z + xv[i].w * w4.w;
    }
    accs[r] = a;
  }
#pragma unroll
  for (int r = 0; r < 8; r++) {
    float a = accs[r];
#pragma unroll
    for (int off = 32; off >= 1; off >>= 1) a += __shfl_xor(a, off);
    if (lane == 0) {
      if (r < 4) qlog[((b << 2) | r) * SEQ + tok] = a;
      else kvlog[((b << 2) | (r - 4)) * SEQ + tok] = a;
    }
  }
}

// ---------------- top-k radix select per (b,g) ----------------
__global__ __launch_bounds__(256) void topk_kernel(
    const float* __restrict__ logits, int K, int* __restrict__ out_idx,
    float* __restrict__ out_score) {
  __shared__ u32 keys[4096];
  __shared__ int eqlist[2048];
  __shared__ int scnt[4];
  __shared__ int s_gt, s_eq;
  int bg = blockIdx.x;
  int tid = threadIdx.x;
  const float* L = logits + bg * 4096;
  for (int e = tid; e < 4096; e += 256) {
    u32 u = __float_as_uint(L[e]);
    keys[e] = (u >> 31) ? ~u : (u | 0x80000000u);
  }
  if (tid == 0) { s_gt = 0; s_eq = 0; }
  __syncthreads();
  u32 prefix = 0;
  int remaining = K;
  for (int bit = 31; bit >= 0; --bit) {
    u32 want = prefix | (1u << bit);
    u32 mask = ~((1u << bit) - 1u);
    int c = 0;
    for (int e = tid; e < 4096; e += 256) c += ((keys[e] & mask) == want) ? 1 : 0;
#pragma unroll
    for (int off = 32; off >= 1; off >>= 1) c += __shfl_xor(c, off);
    if ((tid & 63) == 0) scnt[tid >> 6] = c;
    __syncthreads();
    int total = scnt[0] + scnt[1] + scnt[2] + scnt[3];
    if (total >= remaining) prefix = want;
    else remaining -= total;
    __syncthreads();
  }
  u32 T = prefix;
  for (int e = tid; e < 4096; e += 256) {
    u32 k = keys[e];
    if (k > T) {
      int pos = atomicAdd(&s_gt, 1);
      out_idx[bg * K + pos] = e;
      float v = L[e];
      out_score[bg * K + pos] = 1.0f / (1.0f + __expf(-v));
    } else if (k == T) {
      int p = atomicAdd(&s_eq, 1);
      if (p < 2048) eqlist[p] = e;
    }
  }
  __syncthreads();
  int gt = s_gt;
  int eq = min(s_eq, 2048);
  int need = K - gt;
  for (int i = tid; i < eq; i += 256) {
    int my = eqlist[i];
    int rank = 0;
    for (int j = 0; j < eq; j++) rank += (eqlist[j] < my) ? 1 : 0;
    if (rank < need) {
      int pos = gt + rank;
      out_idx[bg * K + pos] = my;
      float v = L[my];
      out_score[bg * K + pos] = 1.0f / (1.0f + __expf(-v));
    }
  }
}

// ---------------- invert qidx -> qpos (token -> position-in-list, -1 if absent) ----------------
__global__ __launch_bounds__(256) void build_qpos(const int* __restrict__ qidx,
                                                  int* __restrict__ qpos) {
  int i = blockIdx.x * 256 + threadIdx.x;  // 0..16383  (16 bg x 1024 positions)
  int bg = i >> 10, p = i & 1023;
  qpos[bg * 4096 + qidx[i]] = p;
}

// ---------------- shared MFMA GEMM core: 128x128 tile, BK=64, swizzled LDS ----------------
struct Ptr4 { const u16* p[4]; };

__device__ __forceinline__ void mfma_core(Ptr4 A, Ptr4 B, u16* Asm, u16* Bsm,
                                          int ktiles, int tid, f32x4 (&acc)[4][4]) {
  int w = tid >> 6, lane = tid & 63;
  int col = lane & 15, quad = lane >> 4;
  int wr = w >> 1, wc = w & 1;
  for (int kt = 0; kt < ktiles; kt++) {
#pragma unroll
    for (int r = 0; r < 4; r++) {
      char* ldsA = (char*)Asm + (r * 256 + w * 64) * 16;
      __builtin_amdgcn_global_load_lds(
          (const __attribute__((address_space(1))) void*)(A.p[r] + kt * 64),
          (__attribute__((address_space(3))) void*)ldsA, 16, 0, 0);
    }
#pragma unroll
    for (int r = 0; r < 4; r++) {
      char* ldsB = (char*)Bsm + (r * 256 + w * 64) * 16;
      __builtin_amdgcn_global_load_lds(
          (const __attribute__((address_space(1))) void*)(B.p[r] + kt * 64),
          (__attribute__((address_space(3))) void*)ldsB, 16, 0, 0);
    }
    __syncthreads();
#pragma unroll
    for (int k04 = 0; k04 < 8; k04 += 4) {
      bf16x8 af[4], bfr[4];
#pragma unroll
      for (int t = 0; t < 4; t++) {
        int rowa = wr * 64 + t * 16 + col;
        int sp = (quad + k04) ^ (col & 7);
        af[t] = *(const bf16x8*)((const char*)Asm + (rowa * 8 + sp) * 16);
        int rowb = wc * 64 + t * 16 + col;
        bfr[t] = *(const bf16x8*)((const char*)Bsm + (rowb * 8 + sp) * 16);
      }
#pragma unroll
      for (int t = 0; t < 4; t++)
#pragma unroll
        for (int u = 0; u < 4; u++)
          acc[t][u] = __builtin_amdgcn_mfma_f32_16x16x32_bf16(af[t], bfr[u], acc[t][u], 0, 0, 0);
    }
    __syncthreads();
  }
}

// ---------------- q projection: qbuf[bg][1024][512] = gather(xbf) @ wq^T, pre-scaled by DH^-0.5 ----------------
__global__ __launch_bounds__(256) void gemm_qproj(
    const u16* __restrict__ xbf, const int* __restrict__ qidx,
    const u16* __restrict__ wqbf, u16* __restrict__ qbuf) {
  int bg = blockIdx.z, b = bg >> 2, g = bg & 3;
  int row0 = blockIdx.y * 128, col0 = blockIdx.x * 128;
  __shared__ __align__(16) u16 Asm[8192], Bsm[8192];
  __shared__ int ridx[128];
  int tid = threadIdx.x;
  if (tid < 128) ridx[tid] = qidx[bg * NQS + row0 + tid];
  __syncthreads();
  Ptr4 A, B;
#pragma unroll
  for (int r = 0; r < 4; r++) {
    int G = r * 256 + tid;
    int row = G >> 3;
    int seg = (G & 7) ^ (row & 7);
    A.p[r] = xbf + ((size_t)b * SEQ + ridx[row]) * DM + seg * 8;
    B.p[r] = wqbf + ((size_t)g * DI + col0 + row) * DM + seg * 8;
  }
  f32x4 acc[4][4] = {};
  mfma_core(A, B, Asm, Bsm, DM / 64, tid, acc);
  int w = tid >> 6, lane = tid & 63;
  int col = lane & 15, quad = lane >> 4;
  int wr = w >> 1, wc = w & 1;
#pragma unroll
  for (int t = 0; t < 4; t++)
#pragma unroll
    for (int u = 0; u < 4; u++)
#pragma unroll
      for (int r = 0; r < 4; r++) {
        int rowg = row0 + wr * 64 + t * 16 + quad * 4 + r;
        int colg = col0 + wc * 64 + u * 16 + col;
        // pre-scale q by DH^-0.5 = 0.125 (power of two: exact in bf16)
        qbuf[((size_t)bg * NQS + rowg) * DI + colg] = f2bf(acc[t][u][r] * 0.125f);
      }
}

// ---------------- kv projection: K -> kbuf, V^T (scaled) -> vtbuf ----------------
__global__ __launch_bounds__(256) void gemm_kvproj(
    const u16* __restrict__ xbf, const int* __restrict__ kvidx,
    const u16* __restrict__ wkvbf, const float* __restrict__ kvscore,
    u16* __restrict__ kbuf, u16* __restrict__ vtbuf) {
  int bg = blockIdx.z, b = bg >> 2, g = bg & 3;
  int row0 = blockIdx.y * 128, col0 = blockIdx.x * 128;
  __shared__ __align__(16) u16 Asm[8192], Bsm[8192];
  __shared__ int ridx[128];
  int tid = threadIdx.x;
  if (tid < 128) ridx[tid] = kvidx[bg * NKS + row0 + tid];
  __syncthreads();
  Ptr4 A, B;
#pragma unroll
  for (int r = 0; r < 4; r++) {
    int G = r * 256 + tid;
    int row = G >> 3;
    int seg = (G & 7) ^ (row & 7);
    A.p[r] = xbf + ((size_t)b * SEQ + ridx[row]) * DM + seg * 8;
    B.p[r] = wkvbf + ((size_t)g * (2 * DI) + col0 + row) * DM + seg * 8;
  }
  f32x4 acc[4][4] = {};
  mfma_core(A, B, Asm, Bsm, DM / 64, tid, acc);
  int w = tid >> 6, lane = tid & 63;
  int col = lane & 15, quad = lane >> 4;
  int wr = w >> 1, wc = w & 1;
  if (col0 < DI) {
#pragma unroll
    for (int t = 0; t < 4; t++)
#pragma unroll
      for (int u = 0; u < 4; u++)
#pragma unroll
        for (int r = 0; r < 4; r++) {
          int rowg = row0 + wr * 64 + t * 16 + quad * 4 + r;
          int colg = col0 + wc * 64 + u * 16 + col;
          kbuf[((size_t)bg * NKS + rowg) * DI + colg] = f2bf(acc[t][u][r]);
        }
  } else {
#pragma unroll
    for (int t = 0; t < 4; t++)
#pragma unroll
      for (int r = 0; r < 4; r++) {
        int rowg = row0 + wr * 64 + t * 16 + quad * 4 + r;
        float sc = kvscore[bg * NKS + rowg];
#pragma unroll
        for (int u = 0; u < 4; u++) {
          int vc = col0 - DI + wc * 64 + u * 16 + col;  // 0..511
          int h = vc >> 6, d = vc & 63;
          // col index = rowg directly (null column handled analytically in attn)
          vtbuf[(((size_t)bg * NHD + h) * DHD + d) * VTS + rowg] =
              f2bf(acc[t][u][r] * sc);
        }
      }
  }
}

// ---------------- out projection: oproj[z][qpos][d] = (obuf @ wout^T) * qscore, plain stores ----------------
// No atomics: per-(b,g) dense output, gathered by finalize_gather via qpos.
__global__ __launch_bounds__(256) void gemm_outproj(
    const u16* __restrict__ obuf, const u16* __restrict__ woutbf,
    const float* __restrict__ qscore, float* __restrict__ oproj, int bgbase) {
  int z = blockIdx.z, bg = bgbase + z, g = bg & 3;
  int row0 = blockIdx.y * 128, col0 = blockIdx.x * 128;
  __shared__ __align__(16) u16 Asm[8192], Bsm[8192];
  int tid = threadIdx.x;
  Ptr4 A, B;
#pragma unroll
  for (int r = 0; r < 4; r++) {
    int G = r * 256 + tid;
    int row = G >> 3;
    int seg = (G & 7) ^ (row & 7);
    A.p[r] = obuf + ((size_t)bg * NQS + row0 + row) * DI + seg * 8;
    B.p[r] = woutbf + ((size_t)g * DM + col0 + row) * DI + seg * 8;
  }
  f32x4 acc[4][4] = {};
  mfma_core(A, B, Asm, Bsm, DI / 64, tid, acc);
  int w = tid >> 6, lane = tid & 63;
  int col = lane & 15, quad = lane >> 4;
  int wr = w >> 1, wc = w & 1;
  float* obase = oproj + (size_t)z * NQS * DM;
#pragma unroll
  for (int t = 0; t < 4; t++)
#pragma unroll
    for (int r = 0; r < 4; r++) {
      int rowg = row0 + wr * 64 + t * 16 + quad * 4 + r;
      float sc = qscore[bg * NQS + rowg];
      float* orow = obase + (size_t)rowg * DM;
#pragma unroll
      for (int u = 0; u < 4; u++) {
        int colg = col0 + wc * 64 + u * 16 + col;
        orow[colg] = acc[t][u][r] * sc;
      }
    }
}

// ---------------- finalize: gather <=4 group rows, mean, null-token fill ----------------
__global__ __launch_bounds__(256) void finalize_gather(
    const float* __restrict__ oproj, const int* __restrict__ qpos,
    const float* __restrict__ null_token, float* __restrict__ dout, int b0) {
  int blk = blockIdx.x;            // 0..8191 (2 b-values x 4096 tokens)
  int b = b0 + (blk >> 12);
  int tok = blk & 4095;
  int tid = threadIdx.x;
  float4 acc = {0.f, 0.f, 0.f, 0.f};
  int cnt = 0;
#pragma unroll
  for (int g = 0; g < 4; g++) {
    int pos = qpos[(((b << 2) | g)) * 4096 + tok];  // block-uniform
    if (pos >= 0) {
      const float4* row =
          (const float4*)(oproj + (((size_t)((b - b0) * 4 + g)) * NQS + pos) * DM);
      float4 v = row[tid];
      acc.x += v.x; acc.y += v.y; acc.z += v.z; acc.w += v.w;
      cnt++;
    }
  }
  float4* dst = (float4*)(dout + ((size_t)b * SEQ + tok) * DM) + tid;
  if (cnt > 0) {
    float inv = 1.0f / cnt;
    acc.x *= inv; acc.y *= inv; acc.z *= inv; acc.w *= inv;
    *dst = acc;
  } else {
    *dst = ((const float4*)null_token)[tid];
  }
}

// ---------------- MFMA flash attention v3 ----------------
// KVBLK=64 (8 uniform tiles over the 512 real KV rows), null column handled
// analytically in the prologue (m0 = q.k_null, l0 = 1, oacc0 = v_null — exact
// online-softmax init). T14 issue-early/write-late staging. LDS = 27.6 KB ->
// 5 blocks/CU. Deferred l-reduction. q arrives pre-scaled by DH^-0.5.
__global__ __launch_bounds__(256, 4) void attn_mfma(
    const u16* __restrict__ qbuf, const u16* __restrict__ kbuf,
    const u16* __restrict__ vtbuf, const float* __restrict__ null_kv,
    u16* __restrict__ obuf) {
  int qt = blockIdx.x;
  int h = blockIdx.y;
  int bg = blockIdx.z;
  int g = bg & 3;
  int tid = threadIdx.x;
  int w = tid >> 6, lane = tid & 63;
  int col = lane & 15, quad = lane >> 4;

  __shared__ __align__(16) u16 Ks[64][72];
  __shared__ __align__(16) u16 Vts[64][72];
  __shared__ __align__(16) u16 Ps[4][16][72];

  int q0 = qt * 64 + w * 16;
  const u16* qp = qbuf + ((size_t)bg * NQS + q0 + col) * DI + h * DHD + quad * 8;
  bf16x8 qa0 = *(const bf16x8*)qp;
  bf16x8 qa1 = *(const bf16x8*)(qp + 32);

  // --- null-column prologue: exact online-softmax init ---
  const float* kn = null_kv + ((size_t)(0 * NG + g) * NHD + h) * DHD;
  const float* vn = null_kv + ((size_t)(1 * NG + g) * NHD + h) * DHD;
  float sn = 0.f;
#pragma unroll
  for (int i = 0; i < 8; i++) {
    sn += (float)qa0[i] * kn[quad * 8 + i];
    sn += (float)qa1[i] * kn[32 + quad * 8 + i];
  }
  sn += __shfl_xor(sn, 16);
  sn += __shfl_xor(sn, 32);
  float m_run[4], l_lane[4];
  f32x4 oacc[4];
#pragma unroll
  for (int r = 0; r < 4; r++) {
    m_run[r] = __shfl(sn, quad * 4 + r);   // s_null for C-layout row quad*4+r
    l_lane[r] = (col == 0) ? 1.f : 0.f;    // null's p = exp(0) = 1, seeded once
  }
#pragma unroll
  for (int t = 0; t < 4; t++) {
    float v = vn[t * 16 + col];            // oacc0 = 1 * v_null
    f32x4 tmp = {v, v, v, v};
    oacc[t] = tmp;
  }

  // --- staging: 64x64 K tile + 64x64 V^T tile, 32B per thread each ---
  int sr = tid >> 2, ss = tid & 3;
  const u16* kptr = kbuf + ((size_t)bg * NKS + sr) * DI + h * DHD + ss * 16;
  const u16* vptr = vtbuf + (((size_t)bg * NHD + h) * DHD + sr) * VTS + ss * 16;
  uint4* kdst = (uint4*)&Ks[sr][ss * 16];
  uint4* vdst = (uint4*)&Vts[sr][ss * 16];
  uint4 ck0, ck1, cv0, cv1;
  { const uint4* p = (const uint4*)kptr; ck0 = p[0]; ck1 = p[1]; }
  { const uint4* p = (const uint4*)vptr; cv0 = p[0]; cv1 = p[1]; }

  for (int c = 0; c < 8; ++c) {
    kdst[0] = ck0; kdst[1] = ck1;
    vdst[0] = cv0; vdst[1] = cv1;
    uint4 nk0, nk1, nv0, nv1;
    bool pf = (c < 7);
    if (pf) {
      const uint4* p = (const uint4*)(kptr + (size_t)(c + 1) * 64 * DI);
      nk0 = p[0]; nk1 = p[1];
      const uint4* q4 = (const uint4*)(vptr + (c + 1) * 64);
      nv0 = q4[0]; nv1 = q4[1];
    }
    __syncthreads();

    f32x4 sv[4];
#pragma unroll
    for (int t = 0; t < 4; t++) {
      bf16x8 kb0 = *(const bf16x8*)&Ks[t * 16 + col][quad * 8];
      bf16x8 kb1 = *(const bf16x8*)&Ks[t * 16 + col][quad * 8 + 32];
      f32x4 s = {0.f, 0.f, 0.f, 0.f};
      s = __builtin_amdgcn_mfma_f32_16x16x32_bf16(qa0, kb0, s, 0, 0, 0);
      s = __builtin_amdgcn_mfma_f32_16x16x32_bf16(qa1, kb1, s, 0, 0, 0);
      sv[t] = s;
    }
    float alpha[4];
#pragma unroll
    for (int r = 0; r < 4; r++) {
      float m = fmaxf(fmaxf(sv[0][r], sv[1][r]), fmaxf(sv[2][r], sv[3][r]));
      m = fmaxf(m, __shfl_xor(m, 1));
      m = fmaxf(m, __shfl_xor(m, 2));
      m = fmaxf(m, __shfl_xor(m, 4));
      m = fmaxf(m, __shfl_xor(m, 8));
      float mnew = fmaxf(m_run[r], m);
      alpha[r] = __expf(m_run[r] - mnew);
      m_run[r] = mnew;
    }
    float rs[4] = {0.f, 0.f, 0.f, 0.f};
#pragma unroll
    for (int t = 0; t < 4; t++)
#pragma unroll
      for (int r = 0; r < 4; r++) {
        float p = __expf(sv[t][r] - m_run[r]);
        rs[r] += p;
        Ps[w][quad * 4 + r][t * 16 + col] = f2bfh(p);
      }
#pragma unroll
    for (int r = 0; r < 4; r++) l_lane[r] = l_lane[r] * alpha[r] + rs[r];
#pragma unroll
    for (int t = 0; t < 4; t++)
#pragma unroll
      for (int r = 0; r < 4; r++) oacc[t][r] *= alpha[r];

#pragma unroll
    for (int s2 = 0; s2 < 2; s2++) {
      bf16x8 pa = *(const bf16x8*)&Ps[w][col][s2 * 32 + quad * 8];
#pragma unroll
      for (int t = 0; t < 4; t++) {
        bf16x8 vb = *(const bf16x8*)&Vts[t * 16 + col][s2 * 32 + quad * 8];
        oacc[t] = __builtin_amdgcn_mfma_f32_16x16x32_bf16(pa, vb, oacc[t], 0, 0, 0);
      }
    }
    __syncthreads();
    if (pf) { ck0 = nk0; ck1 = nk1; cv0 = nv0; cv1 = nv1; }
  }

  float inv[4];
#pragma unroll
  for (int r = 0; r < 4; r++) {
    float l = l_lane[r];
    l += __shfl_xor(l, 1);
    l += __shfl_xor(l, 2);
    l += __shfl_xor(l, 4);
    l += __shfl_xor(l, 8);
    inv[r] = 1.0f / l;
  }
#pragma unroll
  for (int t = 0; t < 4; t++) {
#pragma unroll
    for (int r = 0; r < 4; r++) {
      obuf[((size_t)bg * NQS + q0 + quad * 4 + r) * DI + h * DHD + t * 16 + col] =
          f2bfh(oacc[t][r] * inv[r]);
    }
  }
}

extern "C" void kernel_launch(void* const* d_in, const int* in_sizes, int n_in,
                              void* d_out, int out_size, void* d_ws, size_t ws_size,
                              hipStream_t stream) {
  const float* x = (const float*)d_in[0];
  const float* wqr = (const float*)d_in[1];
  const float* wkvr = (const float*)d_in[2];
  const float* wq = (const float*)d_in[3];
  const float* wkv = (const float*)d_in[4];
  const float* wout = (const float*)d_in[5];
  const float* nullkv = (const float*)d_in[6];
  const float* nulltok = (const float*)d_in[7];
  float* out = (float*)d_out;
  char* ws = (char*)d_ws;
  // workspace layout (bytes)
  float* qlog = (float*)(ws + 0);                  // 256 KB
  float* kvlog = (float*)(ws + 262144);            // 256 KB
  int* qidx = (int*)(ws + 524288);                 // 64 KB
  int* kvidx = (int*)(ws + 589824);                // 32 KB
  float* qscore = (float*)(ws + 622592);           // 64 KB
  float* kvscore = (float*)(ws + 688128);          // 32 KB
  u16* qbuf = (u16*)(ws + 786432);                 // 16 MB  [16][1024][512]
  u16* kbuf = (u16*)(ws + 17563648);               // 8 MB   [16][512][512]
  u16* vtbuf = (u16*)(ws + 25952256);              // 8.13MB [16][8][64][520]
  u16* obuf = (u16*)(ws + 34476032);               // 16 MB  [16][1024][512]
  u16* xbf = (u16*)(ws + 51253248);                // 32 MB  [4][4096][1024]
  u16* wqbf = (u16*)(ws + 84807680);               // 4 MB   [4][512][1024]
  u16* wkvbf = (u16*)(ws + 89001984);              // 8 MB   [4][1024][1024]
  u16* woutbf = (u16*)(ws + 97390592);             // 4 MB   [4][1024][512]
  // dead-region reuse (stream-ordered, no extra workspace):
  //  - qpos (256 KB) lives in kbuf's region: kbuf is dead after attn_mfma,
  //    and qpos is written (memset+build) only after attn_mfma.
  //  - oproj (32 MiB fp32 [8][1024][1024]) lives exactly in xbf's 32 MiB
  //    region: xbf is dead after gemm_kvproj.
  int* qpos = (int*)(ws + 17563648);
  float* oproj = (float*)(ws + 51253248);

  convert_bf16<<<16384, 256, 0, stream>>>(x, xbf, 4194304);
  convert_bf16<<<2048, 256, 0, stream>>>(wq, wqbf, 524288);
  convert_bf16<<<4096, 256, 0, stream>>>(wkv, wkvbf, 1048576);
  convert_bf16<<<2048, 256, 0, stream>>>(wout, woutbf, 524288);
  router_kernel<<<4096, 256, 0, stream>>>(x, wqr, wkvr, qlog, kvlog);
  topk_kernel<<<16, 256, 0, stream>>>(qlog, NQS, qidx, qscore);
  topk_kernel<<<16, 256, 0, stream>>>(kvlog, NKS, kvidx, kvscore);
  gemm_qproj<<<dim3(4, 8, 16), 256, 0, stream>>>(xbf, qidx, wqbf, qbuf);
  gemm_kvproj<<<dim3(8, 4, 16), 256, 0, stream>>>(xbf, kvidx, wkvbf, kvscore, kbuf, vtbuf);
  attn_mfma<<<dim3(16, 8, 16), 256, 0, stream>>>(qbuf, kbuf, vtbuf, nullkv, obuf);
  // qpos: invert qidx (kbuf region now dead)
  hipMemsetAsync(qpos, 0xFF, 16 * 4096 * sizeof(int), stream);
  build_qpos<<<64, 256, 0, stream>>>(qidx, qpos);
  // batch b in {0,1}: bg 0..7
  gemm_outproj<<<dim3(8, 8, 8), 256, 0, stream>>>(obuf, woutbf, qscore, oproj, 0);
  finalize_gather<<<8192, 256, 0, stream>>>(oproj, qpos, nulltok, out, 0);
  // batch b in {2,3}: bg 8..15
  gemm_outproj<<<dim3(8, 8, 8), 256, 0, stream>>>(obuf, woutbf, qscore, oproj, 8);
  finalize_gather<<<8192, 256, 0, stream>>>(oproj, qpos, nulltok, out, 2);
}

// Round 3
// 381.481 us; speedup vs baseline: 1.2147x; 1.0615x over previous
//
#include <hip/hip_runtime.h>
#include <math.h>

#define NB 4
#define SEQ 4096
#define DM 1024
#define NG 4
#define DI 512
#define NQS 1024
#define NKS 512
#define NHD 8
#define DHD 64
#define VTS 520  // vtbuf row stride (512 cols used, padded)

typedef unsigned int u32;
typedef unsigned short u16;
typedef __bf16 bf16x8 __attribute__((ext_vector_type(8)));
typedef float f32x4 __attribute__((ext_vector_type(4)));

__device__ __forceinline__ float bf2f(u16 u) { return __uint_as_float(((u32)u) << 16); }
__device__ __forceinline__ u16 f2bf(float f) {
  u32 u = __float_as_uint(f);
  u32 r = (u + 0x7FFFu + ((u >> 16) & 1u)) >> 16;
  return (u16)r;
}
// hardware RNE bf16 convert (compiler pairs into v_cvt_pk_bf16_f32)
__device__ __forceinline__ u16 f2bfh(float f) {
  union { __bf16 b; u16 u; } cv;
  cv.b = (__bf16)f;
  return cv.u;
}

// ---------------- fp32 -> bf16 bulk convert (all four tensors, one launch) ----------------
__global__ __launch_bounds__(256) void convert_all(
    const float* __restrict__ x, const float* __restrict__ wq,
    const float* __restrict__ wkv, const float* __restrict__ wout,
    u16* __restrict__ xbf, u16* __restrict__ wqbf, u16* __restrict__ wkvbf,
    u16* __restrict__ woutbf) {
  int i = blockIdx.x * 256 + threadIdx.x;  // float4 index, total 6291456
  const float* src; u16* dst; int off;
  if (i < 4194304)      { src = x;    dst = xbf;    off = i; }
  else if (i < 4718592) { src = wq;   dst = wqbf;   off = i - 4194304; }
  else if (i < 5767168) { src = wkv;  dst = wkvbf;  off = i - 4718592; }
  else                  { src = wout; dst = woutbf; off = i - 5767168; }
  float4 v = ((const float4*)src)[off];
  ushort4 o;
  o.x = f2bf(v.x); o.y = f2bf(v.y); o.z = f2bf(v.z); o.w = f2bf(v.w);
  ((ushort4*)dst)[off] = o;
}

// ---------------- router: logits[b][g][n] for q and kv (fp32 — selection exactness) ----------------
__global__ __launch_bounds__(256) void router_kernel(
    const float* __restrict__ x, const float* __restrict__ wqr,
    const float* __restrict__ wkvr, float* __restrict__ qlog,
    float* __restrict__ kvlog) {
  __shared__ float wsm[8192];
  int tid = threadIdx.x;
  for (int k = tid; k < 8192; k += 256)
    wsm[k] = (k < 4096) ? wqr[k] : wkvr[k - 4096];
  __syncthreads();
  int widx = blockIdx.x * 4 + (tid >> 6);
  int lane = tid & 63;
  int b = widx >> 12, tok = widx & 4095;
  const float4* xr = (const float4*)(x + ((size_t)(b * SEQ + tok)) * DM);
  float4 xv[4];
#pragma unroll
  for (int i = 0; i < 4; i++) xv[i] = xr[i * 64 + lane];
  float accs[8];
#pragma unroll
  for (int r = 0; r < 8; r++) {
    const float4* wr = (const float4*)(wsm + r * 1024);
    float a = 0.f;
#pragma unroll
    for (int i = 0; i < 4; i++) {
      float4 w4 = wr[i * 64 + lane];
      a += xv[i].x * w4.x + xv[i].y * w4.y + xv[i].z * w4.z + xv[i].w * w4.w;
    }
    accs[r] = a;
  }
#pragma unroll
  for (int r = 0; r < 8; r++) {
    float a = accs[r];
#pragma unroll
    for (int off = 32; off >= 1; off >>= 1) a += __shfl_xor(a, off);
    if (lane == 0) {
      if (r < 4) qlog[((b << 2) | r) * SEQ + tok] = a;
      else kvlog[((b << 2) | (r - 4)) * SEQ + tok] = a;
    }
  }
}

// ---------------- top-k radix select per (b,g) ----------------
__global__ __launch_bounds__(256) void topk_kernel(
    const float* __restrict__ logits, int K, int* __restrict__ out_idx,
    float* __restrict__ out_score) {
  __shared__ u32 keys[4096];
  __shared__ int eqlist[2048];
  __shared__ int scnt[4];
  __shared__ int s_gt, s_eq;
  int bg = blockIdx.x;
  int tid = threadIdx.x;
  const float* L = logits + bg * 4096;
  for (int e = tid; e < 4096; e += 256) {
    u32 u = __float_as_uint(L[e]);
    keys[e] = (u >> 31) ? ~u : (u | 0x80000000u);
  }
  if (tid == 0) { s_gt = 0; s_eq = 0; }
  __syncthreads();
  u32 prefix = 0;
  int remaining = K;
  for (int bit = 31; bit >= 0; --bit) {
    u32 want = prefix | (1u << bit);
    u32 mask = ~((1u << bit) - 1u);
    int c = 0;
    for (int e = tid; e < 4096; e += 256) c += ((keys[e] & mask) == want) ? 1 : 0;
#pragma unroll
    for (int off = 32; off >= 1; off >>= 1) c += __shfl_xor(c, off);
    if ((tid & 63) == 0) scnt[tid >> 6] = c;
    __syncthreads();
    int total = scnt[0] + scnt[1] + scnt[2] + scnt[3];
    if (total >= remaining) prefix = want;
    else remaining -= total;
    __syncthreads();
  }
  u32 T = prefix;
  for (int e = tid; e < 4096; e += 256) {
    u32 k = keys[e];
    if (k > T) {
      int pos = atomicAdd(&s_gt, 1);
      out_idx[bg * K + pos] = e;
      float v = L[e];
      out_score[bg * K + pos] = 1.0f / (1.0f + __expf(-v));
    } else if (k == T) {
      int p = atomicAdd(&s_eq, 1);
      if (p < 2048) eqlist[p] = e;
    }
  }
  __syncthreads();
  int gt = s_gt;
  int eq = min(s_eq, 2048);
  int need = K - gt;
  for (int i = tid; i < eq; i += 256) {
    int my = eqlist[i];
    int rank = 0;
    for (int j = 0; j < eq; j++) rank += (eqlist[j] < my) ? 1 : 0;
    if (rank < need) {
      int pos = gt + rank;
      out_idx[bg * K + pos] = my;
      float v = L[my];
      out_score[bg * K + pos] = 1.0f / (1.0f + __expf(-v));
    }
  }
}

// ---------------- invert qidx -> qpos (token -> position-in-list, -1 if absent) ----------------
__global__ __launch_bounds__(256) void build_qpos(const int* __restrict__ qidx,
                                                  int* __restrict__ qpos) {
  int i = blockIdx.x * 256 + threadIdx.x;  // 0..16383  (16 bg x 1024 positions)
  int bg = i >> 10, p = i & 1023;
  qpos[bg * 4096 + qidx[i]] = p;
}

// ---------------- shared MFMA GEMM core: 128x128 tile, BK=64, swizzled LDS ----------------
struct Ptr4 { const u16* p[4]; };

__device__ __forceinline__ void mfma_core(Ptr4 A, Ptr4 B, u16* Asm, u16* Bsm,
                                          int ktiles, int tid, f32x4 (&acc)[4][4]) {
  int w = tid >> 6, lane = tid & 63;
  int col = lane & 15, quad = lane >> 4;
  int wr = w >> 1, wc = w & 1;
  for (int kt = 0; kt < ktiles; kt++) {
#pragma unroll
    for (int r = 0; r < 4; r++) {
      char* ldsA = (char*)Asm + (r * 256 + w * 64) * 16;
      __builtin_amdgcn_global_load_lds(
          (const __attribute__((address_space(1))) void*)(A.p[r] + kt * 64),
          (__attribute__((address_space(3))) void*)ldsA, 16, 0, 0);
    }
#pragma unroll
    for (int r = 0; r < 4; r++) {
      char* ldsB = (char*)Bsm + (r * 256 + w * 64) * 16;
      __builtin_amdgcn_global_load_lds(
          (const __attribute__((address_space(1))) void*)(B.p[r] + kt * 64),
          (__attribute__((address_space(3))) void*)ldsB, 16, 0, 0);
    }
    __syncthreads();
#pragma unroll
    for (int k04 = 0; k04 < 8; k04 += 4) {
      bf16x8 af[4], bfr[4];
#pragma unroll
      for (int t = 0; t < 4; t++) {
        int rowa = wr * 64 + t * 16 + col;
        int sp = (quad + k04) ^ (col & 7);
        af[t] = *(const bf16x8*)((const char*)Asm + (rowa * 8 + sp) * 16);
        int rowb = wc * 64 + t * 16 + col;
        bfr[t] = *(const bf16x8*)((const char*)Bsm + (rowb * 8 + sp) * 16);
      }
#pragma unroll
      for (int t = 0; t < 4; t++)
#pragma unroll
        for (int u = 0; u < 4; u++)
          acc[t][u] = __builtin_amdgcn_mfma_f32_16x16x32_bf16(af[t], bfr[u], acc[t][u], 0, 0, 0);
    }
    __syncthreads();
  }
}

// ---------------- fused q+kv projection (interleaved blocks for CU overlap) ----------------
// even blocks: qbuf[bg][1024][512] = gather(xbf) @ wq^T  (pre-scaled by DH^-0.5)
// odd  blocks: kbuf / vtbuf(scaled V^T) = gather(xbf) @ wkv^T
__global__ __launch_bounds__(256) void gemm_qkvproj(
    const u16* __restrict__ xbf, const int* __restrict__ qidx,
    const int* __restrict__ kvidx, const u16* __restrict__ wqbf,
    const u16* __restrict__ wkvbf, const float* __restrict__ kvscore,
    u16* __restrict__ qbuf, u16* __restrict__ kbuf, u16* __restrict__ vtbuf) {
  __shared__ __align__(16) u16 Asm[8192], Bsm[8192];
  __shared__ int ridx[128];
  int tid = threadIdx.x;
  int id = blockIdx.x;
  bool is_q = (id & 1) == 0;
  int sid = id >> 1;                 // 0..511 either way
  int bg = sid >> 5, r5 = sid & 31;
  int b = bg >> 2, g = bg & 3;
  int w = tid >> 6, lane = tid & 63;
  int col = lane & 15, quad = lane >> 4;
  int wr = w >> 1, wc = w & 1;

  if (is_q) {
    int col0 = (r5 & 3) * 128, row0 = (r5 >> 2) * 128;
    if (tid < 128) ridx[tid] = qidx[bg * NQS + row0 + tid];
    __syncthreads();
    Ptr4 A, B;
#pragma unroll
    for (int r = 0; r < 4; r++) {
      int G = r * 256 + tid;
      int row = G >> 3;
      int seg = (G & 7) ^ (row & 7);
      A.p[r] = xbf + ((size_t)b * SEQ + ridx[row]) * DM + seg * 8;
      B.p[r] = wqbf + ((size_t)g * DI + col0 + row) * DM + seg * 8;
    }
    f32x4 acc[4][4] = {};
    mfma_core(A, B, Asm, Bsm, DM / 64, tid, acc);
#pragma unroll
    for (int t = 0; t < 4; t++)
#pragma unroll
      for (int u = 0; u < 4; u++)
#pragma unroll
        for (int r = 0; r < 4; r++) {
          int rowg = row0 + wr * 64 + t * 16 + quad * 4 + r;
          int colg = col0 + wc * 64 + u * 16 + col;
          // pre-scale q by DH^-0.5 = 0.125 (power of two: exact in bf16)
          qbuf[((size_t)bg * NQS + rowg) * DI + colg] = f2bf(acc[t][u][r] * 0.125f);
        }
  } else {
    int col0 = (r5 & 7) * 128, row0 = (r5 >> 3) * 128;
    if (tid < 128) ridx[tid] = kvidx[bg * NKS + row0 + tid];
    __syncthreads();
    Ptr4 A, B;
#pragma unroll
    for (int r = 0; r < 4; r++) {
      int G = r * 256 + tid;
      int row = G >> 3;
      int seg = (G & 7) ^ (row & 7);
      A.p[r] = xbf + ((size_t)b * SEQ + ridx[row]) * DM + seg * 8;
      B.p[r] = wkvbf + ((size_t)g * (2 * DI) + col0 + row) * DM + seg * 8;
    }
    f32x4 acc[4][4] = {};
    mfma_core(A, B, Asm, Bsm, DM / 64, tid, acc);
    if (col0 < DI) {
#pragma unroll
      for (int t = 0; t < 4; t++)
#pragma unroll
        for (int u = 0; u < 4; u++)
#pragma unroll
          for (int r = 0; r < 4; r++) {
            int rowg = row0 + wr * 64 + t * 16 + quad * 4 + r;
            int colg = col0 + wc * 64 + u * 16 + col;
            kbuf[((size_t)bg * NKS + rowg) * DI + colg] = f2bf(acc[t][u][r]);
          }
    } else {
#pragma unroll
      for (int t = 0; t < 4; t++)
#pragma unroll
        for (int r = 0; r < 4; r++) {
          int rowg = row0 + wr * 64 + t * 16 + quad * 4 + r;
          float sc = kvscore[bg * NKS + rowg];
#pragma unroll
          for (int u = 0; u < 4; u++) {
            int vc = col0 - DI + wc * 64 + u * 16 + col;  // 0..511
            int h = vc >> 6, d = vc & 63;
            vtbuf[(((size_t)bg * NHD + h) * DHD + d) * VTS + rowg] =
                f2bf(acc[t][u][r] * sc);
          }
        }
    }
  }
}

// ---------------- out projection: oproj[z][qpos][d] = (obuf @ wout^T) * qscore, plain stores ----------------
__global__ __launch_bounds__(256) void gemm_outproj(
    const u16* __restrict__ obuf, const u16* __restrict__ woutbf,
    const float* __restrict__ qscore, float* __restrict__ oproj, int bgbase) {
  int z = blockIdx.z, bg = bgbase + z, g = bg & 3;
  int row0 = blockIdx.y * 128, col0 = blockIdx.x * 128;
  __shared__ __align__(16) u16 Asm[8192], Bsm[8192];
  int tid = threadIdx.x;
  Ptr4 A, B;
#pragma unroll
  for (int r = 0; r < 4; r++) {
    int G = r * 256 + tid;
    int row = G >> 3;
    int seg = (G & 7) ^ (row & 7);
    A.p[r] = obuf + ((size_t)bg * NQS + row0 + row) * DI + seg * 8;
    B.p[r] = woutbf + ((size_t)g * DM + col0 + row) * DI + seg * 8;
  }
  f32x4 acc[4][4] = {};
  mfma_core(A, B, Asm, Bsm, DI / 64, tid, acc);
  int w = tid >> 6, lane = tid & 63;
  int col = lane & 15, quad = lane >> 4;
  int wr = w >> 1, wc = w & 1;
  float* obase = oproj + (size_t)z * NQS * DM;
#pragma unroll
  for (int t = 0; t < 4; t++)
#pragma unroll
    for (int r = 0; r < 4; r++) {
      int rowg = row0 + wr * 64 + t * 16 + quad * 4 + r;
      float sc = qscore[bg * NQS + rowg];
      float* orow = obase + (size_t)rowg * DM;
#pragma unroll
      for (int u = 0; u < 4; u++) {
        int colg = col0 + wc * 64 + u * 16 + col;
        orow[colg] = acc[t][u][r] * sc;
      }
    }
}

// ---------------- finalize: gather <=4 group rows, mean, null-token fill ----------------
__global__ __launch_bounds__(256) void finalize_gather(
    const float* __restrict__ oproj, const int* __restrict__ qpos,
    const float* __restrict__ null_token, float* __restrict__ dout, int b0) {
  int blk = blockIdx.x;            // 0..8191 (2 b-values x 4096 tokens)
  int b = b0 + (blk >> 12);
  int tok = blk & 4095;
  int tid = threadIdx.x;
  float4 acc = {0.f, 0.f, 0.f, 0.f};
  int cnt = 0;
#pragma unroll
  for (int g = 0; g < 4; g++) {
    int pos = qpos[(((b << 2) | g)) * 4096 + tok];  // block-uniform
    if (pos >= 0) {
      const float4* row =
          (const float4*)(oproj + (((size_t)((b - b0) * 4 + g)) * NQS + pos) * DM);
      float4 v = row[tid];
      acc.x += v.x; acc.y += v.y; acc.z += v.z; acc.w += v.w;
      cnt++;
    }
  }
  float4* dst = (float4*)(dout + ((size_t)b * SEQ + tok) * DM) + tid;
  if (cnt > 0) {
    float inv = 1.0f / cnt;
    acc.x *= inv; acc.y *= inv; acc.z *= inv; acc.w *= inv;
    *dst = acc;
  } else {
    *dst = ((const float4*)null_token)[tid];
  }
}

// ---------------- MFMA flash attention v4 ----------------
// 32 q per wave (128 q per block, grid qt=8): kb/vb register fragments reused
// across two q-subtiles -> per-q LDS-read/staging/barrier/HBM-refetch cost all
// halve vs v3. Swapped QK (mfma(K,Q) -> S^T): per-lane row-max (in-reg + 2
// shfl), packed b64 Ps stores (4 consecutive k per lane). Defer-max THR=8
// (T13). Null column handled analytically in the prologue. T14
// issue-early/write-late staging (single reg set, overwritten after LDS
// write). LDS = 36.9 KB -> 4 blocks/CU = grid residency.
__global__ __launch_bounds__(256, 4) void attn_mfma(
    const u16* __restrict__ qbuf, const u16* __restrict__ kbuf,
    const u16* __restrict__ vtbuf, const float* __restrict__ null_kv,
    u16* __restrict__ obuf) {
  int qt = blockIdx.x;        // 0..7
  int h = blockIdx.y;         // 0..7
  int bg = blockIdx.z;        // 0..15
  int g = bg & 3;
  int tid = threadIdx.x;
  int w = tid >> 6, lane = tid & 63;
  int col = lane & 15, quad = lane >> 4;

  __shared__ __align__(16) u16 Ks[64][72];
  __shared__ __align__(16) u16 Vts[64][72];
  __shared__ __align__(16) u16 Ps[4][32][72];

  int q0 = qt * 128 + w * 32;
  const u16* qp0 = qbuf + ((size_t)bg * NQS + q0 + col) * DI + h * DHD + quad * 8;
  bf16x8 qa[2][2];
  qa[0][0] = *(const bf16x8*)qp0;
  qa[0][1] = *(const bf16x8*)(qp0 + 32);
  qa[1][0] = *(const bf16x8*)(qp0 + 16 * DI);
  qa[1][1] = *(const bf16x8*)(qp0 + 16 * DI + 32);

  // --- null-column prologue: exact online-softmax init (per-lane q = col) ---
  const float* kn = null_kv + ((size_t)(0 * NG + g) * NHD + h) * DHD;
  const float* vn = null_kv + ((size_t)(1 * NG + g) * NHD + h) * DHD;
  float m_run[2], l_lane[2];
  f32x4 oacc[2][4];
#pragma unroll
  for (int s = 0; s < 2; s++) {
    float sn = 0.f;
#pragma unroll
    for (int i = 0; i < 8; i++) {
      sn += (float)qa[s][0][i] * kn[quad * 8 + i];
      sn += (float)qa[s][1][i] * kn[32 + quad * 8 + i];
    }
    sn += __shfl_xor(sn, 16);
    sn += __shfl_xor(sn, 32);
    m_run[s] = sn;                       // running max = s_null, p_null = 1
    l_lane[s] = (quad == 0) ? 1.f : 0.f; // null's contribution, seeded once
  }
#pragma unroll
  for (int t = 0; t < 4; t++) {
    float v = vn[t * 16 + col];          // oacc0 = 1 * v_null (all q rows)
    f32x4 tmp = {v, v, v, v};
    oacc[0][t] = tmp;
    oacc[1][t] = tmp;
  }

  // --- staging: 64x64 K tile + 64x64 V^T tile, 32B per thread each ---
  int sr = tid >> 2, ss = tid & 3;
  const u16* kptr = kbuf + ((size_t)bg * NKS + sr) * DI + h * DHD + ss * 16;
  const u16* vptr = vtbuf + (((size_t)bg * NHD + h) * DHD + sr) * VTS + ss * 16;
  uint4* kdst = (uint4*)&Ks[sr][ss * 16];
  uint4* vdst = (uint4*)&Vts[sr][ss * 16];
  uint4 ck0, ck1, cv0, cv1;
  { const uint4* p = (const uint4*)kptr; ck0 = p[0]; ck1 = p[1]; }
  { const uint4* p = (const uint4*)vptr; cv0 = p[0]; cv1 = p[1]; }

  for (int c = 0; c < 8; ++c) {
    // write-late: regs (loaded last iteration) -> LDS; then issue-early next
    kdst[0] = ck0; kdst[1] = ck1;
    vdst[0] = cv0; vdst[1] = cv1;
    if (c < 7) {
      const uint4* p = (const uint4*)(kptr + (size_t)(c + 1) * 64 * DI);
      ck0 = p[0]; ck1 = p[1];
      const uint4* q4 = (const uint4*)(vptr + (c + 1) * 64);
      cv0 = q4[0]; cv1 = q4[1];
    }
    __syncthreads();

    // QK^T swapped: sv[s][t] rows = k (quad*4+r within 16-tile t), col = q
    f32x4 sv[2][4];
#pragma unroll
    for (int t = 0; t < 4; t++) {
      bf16x8 kb0 = *(const bf16x8*)&Ks[t * 16 + col][quad * 8];
      bf16x8 kb1 = *(const bf16x8*)&Ks[t * 16 + col][quad * 8 + 32];
      f32x4 z = {0.f, 0.f, 0.f, 0.f};
      f32x4 s0 = __builtin_amdgcn_mfma_f32_16x16x32_bf16(kb0, qa[0][0], z, 0, 0, 0);
      sv[0][t] = __builtin_amdgcn_mfma_f32_16x16x32_bf16(kb1, qa[0][1], s0, 0, 0, 0);
      f32x4 s1 = __builtin_amdgcn_mfma_f32_16x16x32_bf16(kb0, qa[1][0], z, 0, 0, 0);
      sv[1][t] = __builtin_amdgcn_mfma_f32_16x16x32_bf16(kb1, qa[1][1], s1, 0, 0, 0);
    }

    // softmax per q-subtile (per-lane: one q = col, 16 k-values in-register)
#pragma unroll
    for (int s = 0; s < 2; s++) {
      float pm = sv[s][0][0];
#pragma unroll
      for (int t = 0; t < 4; t++)
#pragma unroll
        for (int r = 0; r < 4; r++) pm = fmaxf(pm, sv[s][t][r]);
      pm = fmaxf(pm, __shfl_xor(pm, 16));
      pm = fmaxf(pm, __shfl_xor(pm, 32));
      if (!__all(pm <= m_run[s] + 8.0f)) {   // T13 defer-max
        float mnew = fmaxf(m_run[s], pm);
        float alpha = __expf(m_run[s] - mnew);
        m_run[s] = mnew;
        l_lane[s] *= alpha;
#pragma unroll
        for (int r = 0; r < 4; r++) {
          float a_o = __shfl(alpha, quad * 4 + r);
#pragma unroll
          for (int t = 0; t < 4; t++) oacc[s][t][r] *= a_o;
        }
      }
      float rs = 0.f;
#pragma unroll
      for (int t = 0; t < 4; t++) {
        float p0 = __expf(sv[s][t][0] - m_run[s]);
        float p1 = __expf(sv[s][t][1] - m_run[s]);
        float p2 = __expf(sv[s][t][2] - m_run[s]);
        float p3 = __expf(sv[s][t][3] - m_run[s]);
        rs += (p0 + p1) + (p2 + p3);
        u32 lo = (u32)f2bfh(p0) | ((u32)f2bfh(p1) << 16);
        u32 hi = (u32)f2bfh(p2) | ((u32)f2bfh(p3) << 16);
        // 4 consecutive k per lane -> one b64 store
        *(uint2*)&Ps[w][s * 16 + col][t * 16 + quad * 4] = make_uint2(lo, hi);
      }
      l_lane[s] += rs;
    }

    // PV: vb fragments reused for both q-subtiles
#pragma unroll
    for (int s2 = 0; s2 < 2; s2++) {
      bf16x8 pa0 = *(const bf16x8*)&Ps[w][col][s2 * 32 + quad * 8];
      bf16x8 pa1 = *(const bf16x8*)&Ps[w][16 + col][s2 * 32 + quad * 8];
#pragma unroll
      for (int t = 0; t < 4; t++) {
        bf16x8 vb = *(const bf16x8*)&Vts[t * 16 + col][s2 * 32 + quad * 8];
        oacc[0][t] = __builtin_amdgcn_mfma_f32_16x16x32_bf16(pa0, vb, oacc[0][t], 0, 0, 0);
        oacc[1][t] = __builtin_amdgcn_mfma_f32_16x16x32_bf16(pa1, vb, oacc[1][t], 0, 0, 0);
      }
    }
    __syncthreads();
  }

  // epilogue: reduce l across quads, redistribute to C layout, write
#pragma unroll
  for (int s = 0; s < 2; s++) {
    float l = l_lane[s];
    l += __shfl_xor(l, 16);
    l += __shfl_xor(l, 32);
    float inv = 1.0f / l;
#pragma unroll
    for (int r = 0; r < 4; r++) {
      float ir = __shfl(inv, quad * 4 + r);
#pragma unroll
      for (int t = 0; t < 4; t++) {
        obuf[((size_t)bg * NQS + q0 + s * 16 + quad * 4 + r) * DI + h * DHD +
             t * 16 + col] = f2bfh(oacc[s][t][r] * ir);
      }
    }
  }
}

extern "C" void kernel_launch(void* const* d_in, const int* in_sizes, int n_in,
                              void* d_out, int out_size, void* d_ws, size_t ws_size,
                              hipStream_t stream) {
  const float* x = (const float*)d_in[0];
  const float* wqr = (const float*)d_in[1];
  const float* wkvr = (const float*)d_in[2];
  const float* wq = (const float*)d_in[3];
  const float* wkv = (const float*)d_in[4];
  const float* wout = (const float*)d_in[5];
  const float* nullkv = (const float*)d_in[6];
  const float* nulltok = (const float*)d_in[7];
  float* out = (float*)d_out;
  char* ws = (char*)d_ws;
  // workspace layout (bytes)
  float* qlog = (float*)(ws + 0);                  // 256 KB
  float* kvlog = (float*)(ws + 262144);            // 256 KB
  int* qidx = (int*)(ws + 524288);                 // 64 KB
  int* kvidx = (int*)(ws + 589824);                // 32 KB
  float* qscore = (float*)(ws + 622592);           // 64 KB
  float* kvscore = (float*)(ws + 688128);          // 32 KB
  u16* qbuf = (u16*)(ws + 786432);                 // 16 MB  [16][1024][512]
  u16* kbuf = (u16*)(ws + 17563648);               // 8 MB   [16][512][512]
  u16* vtbuf = (u16*)(ws + 25952256);              // 8.13MB [16][8][64][520]
  u16* obuf = (u16*)(ws + 34476032);               // 16 MB  [16][1024][512]
  u16* xbf = (u16*)(ws + 51253248);                // 32 MB  [4][4096][1024]
  u16* wqbf = (u16*)(ws + 84807680);               // 4 MB   [4][512][1024]
  u16* wkvbf = (u16*)(ws + 89001984);              // 8 MB   [4][1024][1024]
  u16* woutbf = (u16*)(ws + 97390592);             // 4 MB   [4][1024][512]
  // dead-region reuse (stream-ordered):
  //  - qpos (256 KB) in kbuf's region (kbuf dead after attn_mfma)
  //  - oproj (32 MiB fp32 [8][1024][1024]) in xbf's region (dead after proj)
  int* qpos = (int*)(ws + 17563648);
  float* oproj = (float*)(ws + 51253248);

  convert_all<<<24576, 256, 0, stream>>>(x, wq, wkv, wout, xbf, wqbf, wkvbf, woutbf);
  router_kernel<<<4096, 256, 0, stream>>>(x, wqr, wkvr, qlog, kvlog);
  topk_kernel<<<16, 256, 0, stream>>>(qlog, NQS, qidx, qscore);
  topk_kernel<<<16, 256, 0, stream>>>(kvlog, NKS, kvidx, kvscore);
  gemm_qkvproj<<<1024, 256, 0, stream>>>(xbf, qidx, kvidx, wqbf, wkvbf, kvscore,
                                         qbuf, kbuf, vtbuf);
  attn_mfma<<<dim3(8, 8, 16), 256, 0, stream>>>(qbuf, kbuf, vtbuf, nullkv, obuf);
  // qpos: invert qidx (kbuf region now dead)
  hipMemsetAsync(qpos, 0xFF, 16 * 4096 * sizeof(int), stream);
  build_qpos<<<64, 256, 0, stream>>>(qidx, qpos);
  // batch b in {0,1}: bg 0..7
  gemm_outproj<<<dim3(8, 8, 8), 256, 0, stream>>>(obuf, woutbf, qscore, oproj, 0);
  finalize_gather<<<8192, 256, 0, stream>>>(oproj, qpos, nulltok, out, 0);
  // batch b in {2,3}: bg 8..15
  gemm_outproj<<<dim3(8, 8, 8), 256, 0, stream>>>(obuf, woutbf, qscore, oproj, 8);
  finalize_gather<<<8192, 256, 0, stream>>>(oproj, qpos, nulltok, out, 2);
}

// Round 4
// 339.429 us; speedup vs baseline: 1.3652x; 1.1239x over previous
//
#include <hip/hip_runtime.h>
#include <math.h>

#define NB 4
#define SEQ 4096
#define DM 1024
#define NG 4
#define DI 512
#define NQS 1024
#define NKS 512
#define NHD 8
#define DHD 64
#define VTS 520  // vtbuf row stride (512 cols used, padded)

typedef unsigned int u32;
typedef unsigned short u16;
typedef __bf16 bf16x8 __attribute__((ext_vector_type(8)));
typedef float f32x4 __attribute__((ext_vector_type(4)));

__device__ __forceinline__ float bf2f(u16 u) { return __uint_as_float(((u32)u) << 16); }
__device__ __forceinline__ u16 f2bf(float f) {
  u32 u = __float_as_uint(f);
  u32 r = (u + 0x7FFFu + ((u >> 16) & 1u)) >> 16;
  return (u16)r;
}
// hardware RNE bf16 convert (compiler pairs into v_cvt_pk_bf16_f32)
__device__ __forceinline__ u16 f2bfh(float f) {
  union { __bf16 b; u16 u; } cv;
  cv.b = (__bf16)f;
  return cv.u;
}

// ---------------- router + full bf16 conversion (x read exactly once) ----------------
// Per wave: one token row -> q/kv logits AND xbf row (bit-identical f2bf).
// Grid-strided weight conversion folded in (wq/wkv/wout -> bf16).
__global__ __launch_bounds__(256) void router_kernel(
    const float* __restrict__ x, const float* __restrict__ wqr,
    const float* __restrict__ wkvr, float* __restrict__ qlog,
    float* __restrict__ kvlog, u16* __restrict__ xbf,
    const float* __restrict__ wq, const float* __restrict__ wkv,
    const float* __restrict__ wout, u16* __restrict__ wqbf,
    u16* __restrict__ wkvbf, u16* __restrict__ woutbf) {
  __shared__ float wsm[8192];
  int tid = threadIdx.x;
  for (int k = tid; k < 8192; k += 256)
    wsm[k] = (k < 4096) ? wqr[k] : wkvr[k - 4096];

  // weight conversion: 2,097,152 float4 total over 4096 blocks = 512/block
#pragma unroll
  for (int j = 0; j < 2; j++) {
    int idx = blockIdx.x * 512 + j * 256 + tid;
    const float* src; u16* dst; int off;
    if (idx < 524288)        { src = wq;   dst = wqbf;   off = idx; }
    else if (idx < 1572864)  { src = wkv;  dst = wkvbf;  off = idx - 524288; }
    else                     { src = wout; dst = woutbf; off = idx - 1572864; }
    float4 v = ((const float4*)src)[off];
    ushort4 o;
    o.x = f2bf(v.x); o.y = f2bf(v.y); o.z = f2bf(v.z); o.w = f2bf(v.w);
    ((ushort4*)dst)[off] = o;
  }
  __syncthreads();

  int widx = blockIdx.x * 4 + (tid >> 6);
  int lane = tid & 63;
  int b = widx >> 12, tok = widx & 4095;
  const float4* xr = (const float4*)(x + ((size_t)(b * SEQ + tok)) * DM);
  float4 xv[4];
#pragma unroll
  for (int i = 0; i < 4; i++) xv[i] = xr[i * 64 + lane];
  // emit bf16 row (coalesced: consecutive lanes -> consecutive ushort4)
  ushort4* xrow = (ushort4*)(xbf + ((size_t)(b * SEQ + tok)) * DM);
#pragma unroll
  for (int i = 0; i < 4; i++) {
    ushort4 o;
    o.x = f2bf(xv[i].x); o.y = f2bf(xv[i].y);
    o.z = f2bf(xv[i].z); o.w = f2bf(xv[i].w);
    xrow[i * 64 + lane] = o;
  }
  float accs[8];
#pragma unroll
  for (int r = 0; r < 8; r++) {
    const float4* wr = (const float4*)(wsm + r * 1024);
    float a = 0.f;
#pragma unroll
    for (int i = 0; i < 4; i++) {
      float4 w4 = wr[i * 64 + lane];
      a += xv[i].x * w4.x + xv[i].y * w4.y + xv[i].z * w4.z + xv[i].w * w4.w;
    }
    accs[r] = a;
  }
#pragma unroll
  for (int r = 0; r < 8; r++) {
    float a = accs[r];
#pragma unroll
    for (int off = 32; off >= 1; off >>= 1) a += __shfl_xor(a, off);
    if (lane == 0) {
      if (r < 4) qlog[((b << 2) | r) * SEQ + tok] = a;
      else kvlog[((b << 2) | (r - 4)) * SEQ + tok] = a;
    }
  }
}

// ---------------- merged top-k radix select: blocks 0-15 q (K=1024), 16-31 kv (K=512) ----------------
__global__ __launch_bounds__(256) void topk_kernel(
    const float* __restrict__ qlog, const float* __restrict__ kvlog,
    int* __restrict__ qidx, float* __restrict__ qscore,
    int* __restrict__ kvidx, float* __restrict__ kvscore) {
  __shared__ u32 keys[4096];
  __shared__ int eqlist[2048];
  __shared__ int scnt[4];
  __shared__ int s_gt, s_eq;
  int which = blockIdx.x >> 4;
  int bg = blockIdx.x & 15;
  int K = (which == 0) ? NQS : NKS;
  const float* L = ((which == 0) ? qlog : kvlog) + bg * 4096;
  int* out_idx = ((which == 0) ? qidx : kvidx) + bg * K;
  float* out_score = ((which == 0) ? qscore : kvscore) + bg * K;
  int tid = threadIdx.x;
  for (int e = tid; e < 4096; e += 256) {
    u32 u = __float_as_uint(L[e]);
    keys[e] = (u >> 31) ? ~u : (u | 0x80000000u);
  }
  if (tid == 0) { s_gt = 0; s_eq = 0; }
  __syncthreads();
  u32 prefix = 0;
  int remaining = K;
  for (int bit = 31; bit >= 0; --bit) {
    u32 want = prefix | (1u << bit);
    u32 mask = ~((1u << bit) - 1u);
    int c = 0;
    for (int e = tid; e < 4096; e += 256) c += ((keys[e] & mask) == want) ? 1 : 0;
#pragma unroll
    for (int off = 32; off >= 1; off >>= 1) c += __shfl_xor(c, off);
    if ((tid & 63) == 0) scnt[tid >> 6] = c;
    __syncthreads();
    int total = scnt[0] + scnt[1] + scnt[2] + scnt[3];
    if (total >= remaining) prefix = want;
    else remaining -= total;
    __syncthreads();
  }
  u32 T = prefix;
  for (int e = tid; e < 4096; e += 256) {
    u32 k = keys[e];
    if (k > T) {
      int pos = atomicAdd(&s_gt, 1);
      out_idx[pos] = e;
      float v = L[e];
      out_score[pos] = 1.0f / (1.0f + __expf(-v));
    } else if (k == T) {
      int p = atomicAdd(&s_eq, 1);
      if (p < 2048) eqlist[p] = e;
    }
  }
  __syncthreads();
  int gt = s_gt;
  int eq = min(s_eq, 2048);
  int need = K - gt;
  for (int i = tid; i < eq; i += 256) {
    int my = eqlist[i];
    int rank = 0;
    for (int j = 0; j < eq; j++) rank += (eqlist[j] < my) ? 1 : 0;
    if (rank < need) {
      int pos = gt + rank;
      out_idx[pos] = my;
      float v = L[my];
      out_score[pos] = 1.0f / (1.0f + __expf(-v));
    }
  }
}

// ---------------- qpos: init -1 + scatter positions, one block per bg ----------------
__global__ __launch_bounds__(256) void qpos_build(const int* __restrict__ qidx,
                                                  int* __restrict__ qpos) {
  int bg = blockIdx.x;
  int tid = threadIdx.x;
  int* base = qpos + bg * 4096;
  for (int i = tid; i < 4096; i += 256) base[i] = -1;
  __syncthreads();
  for (int p = tid; p < NQS; p += 256) base[qidx[bg * NQS + p]] = p;
}

// ---------------- shared MFMA GEMM core: 128x128 tile, BK=64, swizzled LDS ----------------
struct Ptr4 { const u16* p[4]; };

__device__ __forceinline__ void mfma_core(Ptr4 A, Ptr4 B, u16* Asm, u16* Bsm,
                                          int ktiles, int tid, f32x4 (&acc)[4][4]) {
  int w = tid >> 6, lane = tid & 63;
  int col = lane & 15, quad = lane >> 4;
  int wr = w >> 1, wc = w & 1;
  for (int kt = 0; kt < ktiles; kt++) {
#pragma unroll
    for (int r = 0; r < 4; r++) {
      char* ldsA = (char*)Asm + (r * 256 + w * 64) * 16;
      __builtin_amdgcn_global_load_lds(
          (const __attribute__((address_space(1))) void*)(A.p[r] + kt * 64),
          (__attribute__((address_space(3))) void*)ldsA, 16, 0, 0);
    }
#pragma unroll
    for (int r = 0; r < 4; r++) {
      char* ldsB = (char*)Bsm + (r * 256 + w * 64) * 16;
      __builtin_amdgcn_global_load_lds(
          (const __attribute__((address_space(1))) void*)(B.p[r] + kt * 64),
          (__attribute__((address_space(3))) void*)ldsB, 16, 0, 0);
    }
    __syncthreads();
#pragma unroll
    for (int k04 = 0; k04 < 8; k04 += 4) {
      bf16x8 af[4], bfr[4];
#pragma unroll
      for (int t = 0; t < 4; t++) {
        int rowa = wr * 64 + t * 16 + col;
        int sp = (quad + k04) ^ (col & 7);
        af[t] = *(const bf16x8*)((const char*)Asm + (rowa * 8 + sp) * 16);
        int rowb = wc * 64 + t * 16 + col;
        bfr[t] = *(const bf16x8*)((const char*)Bsm + (rowb * 8 + sp) * 16);
      }
#pragma unroll
      for (int t = 0; t < 4; t++)
#pragma unroll
        for (int u = 0; u < 4; u++)
          acc[t][u] = __builtin_amdgcn_mfma_f32_16x16x32_bf16(af[t], bfr[u], acc[t][u], 0, 0, 0);
    }
    __syncthreads();
  }
}

// ---------------- fused q+kv projection, XCD-grouped ----------------
// grp = blockIdx & 7 (per-XCD, bid%8 round-robin heuristic): grp<4 -> qproj
// of group g=grp; grp>=4 -> kvproj of g=grp-4. Each XCD's weight slice is
// 1-2 MB -> L2-resident, no cross-XCD weight refetch.
__global__ __launch_bounds__(256) void gemm_qkvproj(
    const u16* __restrict__ xbf, const int* __restrict__ qidx,
    const int* __restrict__ kvidx, const u16* __restrict__ wqbf,
    const u16* __restrict__ wkvbf, const float* __restrict__ kvscore,
    u16* __restrict__ qbuf, u16* __restrict__ kbuf, u16* __restrict__ vtbuf) {
  __shared__ __align__(16) u16 Asm[8192], Bsm[8192];
  __shared__ int ridx[128];
  int tid = threadIdx.x;
  int grp = blockIdx.x & 7;
  int local = blockIdx.x >> 3;       // 0..127
  bool is_q = grp < 4;
  int g = grp & 3;
  int b = local >> 5, r5 = local & 31;
  int bg = (b << 2) | g;
  int w = tid >> 6, lane = tid & 63;
  int col = lane & 15, quad = lane >> 4;
  int wr = w >> 1, wc = w & 1;

  if (is_q) {
    int col0 = (r5 & 3) * 128, row0 = (r5 >> 2) * 128;
    if (tid < 128) ridx[tid] = qidx[bg * NQS + row0 + tid];
    __syncthreads();
    Ptr4 A, B;
#pragma unroll
    for (int r = 0; r < 4; r++) {
      int G = r * 256 + tid;
      int row = G >> 3;
      int seg = (G & 7) ^ (row & 7);
      A.p[r] = xbf + ((size_t)b * SEQ + ridx[row]) * DM + seg * 8;
      B.p[r] = wqbf + ((size_t)g * DI + col0 + row) * DM + seg * 8;
    }
    f32x4 acc[4][4] = {};
    mfma_core(A, B, Asm, Bsm, DM / 64, tid, acc);
#pragma unroll
    for (int t = 0; t < 4; t++)
#pragma unroll
      for (int u = 0; u < 4; u++)
#pragma unroll
        for (int r = 0; r < 4; r++) {
          int rowg = row0 + wr * 64 + t * 16 + quad * 4 + r;
          int colg = col0 + wc * 64 + u * 16 + col;
          // pre-scale q by DH^-0.5 = 0.125 (power of two: exact in bf16)
          qbuf[((size_t)bg * NQS + rowg) * DI + colg] = f2bf(acc[t][u][r] * 0.125f);
        }
  } else {
    int col0 = (r5 & 7) * 128, row0 = (r5 >> 3) * 128;
    if (tid < 128) ridx[tid] = kvidx[bg * NKS + row0 + tid];
    __syncthreads();
    Ptr4 A, B;
#pragma unroll
    for (int r = 0; r < 4; r++) {
      int G = r * 256 + tid;
      int row = G >> 3;
      int seg = (G & 7) ^ (row & 7);
      A.p[r] = xbf + ((size_t)b * SEQ + ridx[row]) * DM + seg * 8;
      B.p[r] = wkvbf + ((size_t)g * (2 * DI) + col0 + row) * DM + seg * 8;
    }
    f32x4 acc[4][4] = {};
    mfma_core(A, B, Asm, Bsm, DM / 64, tid, acc);
    if (col0 < DI) {
#pragma unroll
      for (int t = 0; t < 4; t++)
#pragma unroll
        for (int u = 0; u < 4; u++)
#pragma unroll
          for (int r = 0; r < 4; r++) {
            int rowg = row0 + wr * 64 + t * 16 + quad * 4 + r;
            int colg = col0 + wc * 64 + u * 16 + col;
            kbuf[((size_t)bg * NKS + rowg) * DI + colg] = f2bf(acc[t][u][r]);
          }
    } else {
#pragma unroll
      for (int t = 0; t < 4; t++)
#pragma unroll
        for (int r = 0; r < 4; r++) {
          int rowg = row0 + wr * 64 + t * 16 + quad * 4 + r;
          float sc = kvscore[bg * NKS + rowg];
#pragma unroll
          for (int u = 0; u < 4; u++) {
            int vc = col0 - DI + wc * 64 + u * 16 + col;  // 0..511
            int h = vc >> 6, d = vc & 63;
            vtbuf[(((size_t)bg * NHD + h) * DHD + d) * VTS + rowg] =
                f2bf(acc[t][u][r] * sc);
          }
        }
    }
  }
}

// ---------------- out projection: oproj[z][qpos][d] = (obuf @ wout^T) * qscore, plain stores ----------------
__global__ __launch_bounds__(256) void gemm_outproj(
    const u16* __restrict__ obuf, const u16* __restrict__ woutbf,
    const float* __restrict__ qscore, float* __restrict__ oproj, int bgbase) {
  int z = blockIdx.z, bg = bgbase + z, g = bg & 3;
  int row0 = blockIdx.y * 128, col0 = blockIdx.x * 128;
  __shared__ __align__(16) u16 Asm[8192], Bsm[8192];
  int tid = threadIdx.x;
  Ptr4 A, B;
#pragma unroll
  for (int r = 0; r < 4; r++) {
    int G = r * 256 + tid;
    int row = G >> 3;
    int seg = (G & 7) ^ (row & 7);
    A.p[r] = obuf + ((size_t)bg * NQS + row0 + row) * DI + seg * 8;
    B.p[r] = woutbf + ((size_t)g * DM + col0 + row) * DI + seg * 8;
  }
  f32x4 acc[4][4] = {};
  mfma_core(A, B, Asm, Bsm, DI / 64, tid, acc);
  int w = tid >> 6, lane = tid & 63;
  int col = lane & 15, quad = lane >> 4;
  int wr = w >> 1, wc = w & 1;
  float* obase = oproj + (size_t)z * NQS * DM;
#pragma unroll
  for (int t = 0; t < 4; t++)
#pragma unroll
    for (int r = 0; r < 4; r++) {
      int rowg = row0 + wr * 64 + t * 16 + quad * 4 + r;
      float sc = qscore[bg * NQS + rowg];
      float* orow = obase + (size_t)rowg * DM;
#pragma unroll
      for (int u = 0; u < 4; u++) {
        int colg = col0 + wc * 64 + u * 16 + col;
        orow[colg] = acc[t][u][r] * sc;
      }
    }
}

// ---------------- finalize: gather <=4 group rows, mean, null-token fill ----------------
__global__ __launch_bounds__(256) void finalize_gather(
    const float* __restrict__ oproj, const int* __restrict__ qpos,
    const float* __restrict__ null_token, float* __restrict__ dout, int b0) {
  int blk = blockIdx.x;            // 0..8191 (2 b-values x 4096 tokens)
  int b = b0 + (blk >> 12);
  int tok = blk & 4095;
  int tid = threadIdx.x;
  float4 acc = {0.f, 0.f, 0.f, 0.f};
  int cnt = 0;
#pragma unroll
  for (int g = 0; g < 4; g++) {
    int pos = qpos[(((b << 2) | g)) * 4096 + tok];  // block-uniform
    if (pos >= 0) {
      const float4* row =
          (const float4*)(oproj + (((size_t)((b - b0) * 4 + g)) * NQS + pos) * DM);
      float4 v = row[tid];
      acc.x += v.x; acc.y += v.y; acc.z += v.z; acc.w += v.w;
      cnt++;
    }
  }
  float4* dst = (float4*)(dout + ((size_t)b * SEQ + tok) * DM) + tid;
  if (cnt > 0) {
    float inv = 1.0f / cnt;
    acc.x *= inv; acc.y *= inv; acc.z *= inv; acc.w *= inv;
    *dst = acc;
  } else {
    *dst = ((const float4*)null_token)[tid];
  }
}

// ---------------- MFMA flash attention v4 ----------------
// 32 q per wave (128 q per block, grid qt=8): kb/vb register fragments reused
// across two q-subtiles. Swapped QK (mfma(K,Q) -> S^T): per-lane row-max,
// packed b64 Ps stores. Defer-max THR=8 (T13). Null column analytic prologue.
// T14 issue-early/write-late staging. LDS 36.9 KB -> 4 blocks/CU.
__global__ __launch_bounds__(256, 4) void attn_mfma(
    const u16* __restrict__ qbuf, const u16* __restrict__ kbuf,
    const u16* __restrict__ vtbuf, const float* __restrict__ null_kv,
    u16* __restrict__ obuf) {
  int qt = blockIdx.x;        // 0..7
  int h = blockIdx.y;         // 0..7
  int bg = blockIdx.z;        // 0..15
  int g = bg & 3;
  int tid = threadIdx.x;
  int w = tid >> 6, lane = tid & 63;
  int col = lane & 15, quad = lane >> 4;

  __shared__ __align__(16) u16 Ks[64][72];
  __shared__ __align__(16) u16 Vts[64][72];
  __shared__ __align__(16) u16 Ps[4][32][72];

  int q0 = qt * 128 + w * 32;
  const u16* qp0 = qbuf + ((size_t)bg * NQS + q0 + col) * DI + h * DHD + quad * 8;
  bf16x8 qa[2][2];
  qa[0][0] = *(const bf16x8*)qp0;
  qa[0][1] = *(const bf16x8*)(qp0 + 32);
  qa[1][0] = *(const bf16x8*)(qp0 + 16 * DI);
  qa[1][1] = *(const bf16x8*)(qp0 + 16 * DI + 32);

  // --- null-column prologue: exact online-softmax init (per-lane q = col) ---
  const float* kn = null_kv + ((size_t)(0 * NG + g) * NHD + h) * DHD;
  const float* vn = null_kv + ((size_t)(1 * NG + g) * NHD + h) * DHD;
  float m_run[2], l_lane[2];
  f32x4 oacc[2][4];
#pragma unroll
  for (int s = 0; s < 2; s++) {
    float sn = 0.f;
#pragma unroll
    for (int i = 0; i < 8; i++) {
      sn += (float)qa[s][0][i] * kn[quad * 8 + i];
      sn += (float)qa[s][1][i] * kn[32 + quad * 8 + i];
    }
    sn += __shfl_xor(sn, 16);
    sn += __shfl_xor(sn, 32);
    m_run[s] = sn;                       // running max = s_null, p_null = 1
    l_lane[s] = (quad == 0) ? 1.f : 0.f; // null's contribution, seeded once
  }
#pragma unroll
  for (int t = 0; t < 4; t++) {
    float v = vn[t * 16 + col];          // oacc0 = 1 * v_null (all q rows)
    f32x4 tmp = {v, v, v, v};
    oacc[0][t] = tmp;
    oacc[1][t] = tmp;
  }

  // --- staging: 64x64 K tile + 64x64 V^T tile, 32B per thread each ---
  int sr = tid >> 2, ss = tid & 3;
  const u16* kptr = kbuf + ((size_t)bg * NKS + sr) * DI + h * DHD + ss * 16;
  const u16* vptr = vtbuf + (((size_t)bg * NHD + h) * DHD + sr) * VTS + ss * 16;
  uint4* kdst = (uint4*)&Ks[sr][ss * 16];
  uint4* vdst = (uint4*)&Vts[sr][ss * 16];
  uint4 ck0, ck1, cv0, cv1;
  { const uint4* p = (const uint4*)kptr; ck0 = p[0]; ck1 = p[1]; }
  { const uint4* p = (const uint4*)vptr; cv0 = p[0]; cv1 = p[1]; }

  for (int c = 0; c < 8; ++c) {
    // write-late: regs (loaded last iteration) -> LDS; then issue-early next
    kdst[0] = ck0; kdst[1] = ck1;
    vdst[0] = cv0; vdst[1] = cv1;
    if (c < 7) {
      const uint4* p = (const uint4*)(kptr + (size_t)(c + 1) * 64 * DI);
      ck0 = p[0]; ck1 = p[1];
      const uint4* q4 = (const uint4*)(vptr + (c + 1) * 64);
      cv0 = q4[0]; cv1 = q4[1];
    }
    __syncthreads();

    // QK^T swapped: sv[s][t] rows = k (quad*4+r within 16-tile t), col = q
    f32x4 sv[2][4];
#pragma unroll
    for (int t = 0; t < 4; t++) {
      bf16x8 kb0 = *(const bf16x8*)&Ks[t * 16 + col][quad * 8];
      bf16x8 kb1 = *(const bf16x8*)&Ks[t * 16 + col][quad * 8 + 32];
      f32x4 z = {0.f, 0.f, 0.f, 0.f};
      f32x4 s0 = __builtin_amdgcn_mfma_f32_16x16x32_bf16(kb0, qa[0][0], z, 0, 0, 0);
      sv[0][t] = __builtin_amdgcn_mfma_f32_16x16x32_bf16(kb1, qa[0][1], s0, 0, 0, 0);
      f32x4 s1 = __builtin_amdgcn_mfma_f32_16x16x32_bf16(kb0, qa[1][0], z, 0, 0, 0);
      sv[1][t] = __builtin_amdgcn_mfma_f32_16x16x32_bf16(kb1, qa[1][1], s1, 0, 0, 0);
    }

    // softmax per q-subtile (per-lane: one q = col, 16 k-values in-register)
#pragma unroll
    for (int s = 0; s < 2; s++) {
      float pm = sv[s][0][0];
#pragma unroll
      for (int t = 0; t < 4; t++)
#pragma unroll
        for (int r = 0; r < 4; r++) pm = fmaxf(pm, sv[s][t][r]);
      pm = fmaxf(pm, __shfl_xor(pm, 16));
      pm = fmaxf(pm, __shfl_xor(pm, 32));
      if (!__all(pm <= m_run[s] + 8.0f)) {   // T13 defer-max
        float mnew = fmaxf(m_run[s], pm);
        float alpha = __expf(m_run[s] - mnew);
        m_run[s] = mnew;
        l_lane[s] *= alpha;
#pragma unroll
        for (int r = 0; r < 4; r++) {
          float a_o = __shfl(alpha, quad * 4 + r);
#pragma unroll
          for (int t = 0; t < 4; t++) oacc[s][t][r] *= a_o;
        }
      }
      float rs = 0.f;
#pragma unroll
      for (int t = 0; t < 4; t++) {
        float p0 = __expf(sv[s][t][0] - m_run[s]);
        float p1 = __expf(sv[s][t][1] - m_run[s]);
        float p2 = __expf(sv[s][t][2] - m_run[s]);
        float p3 = __expf(sv[s][t][3] - m_run[s]);
        rs += (p0 + p1) + (p2 + p3);
        u32 lo = (u32)f2bfh(p0) | ((u32)f2bfh(p1) << 16);
        u32 hi = (u32)f2bfh(p2) | ((u32)f2bfh(p3) << 16);
        // 4 consecutive k per lane -> one b64 store
        *(uint2*)&Ps[w][s * 16 + col][t * 16 + quad * 4] = make_uint2(lo, hi);
      }
      l_lane[s] += rs;
    }

    // PV: vb fragments reused for both q-subtiles
#pragma unroll
    for (int s2 = 0; s2 < 2; s2++) {
      bf16x8 pa0 = *(const bf16x8*)&Ps[w][col][s2 * 32 + quad * 8];
      bf16x8 pa1 = *(const bf16x8*)&Ps[w][16 + col][s2 * 32 + quad * 8];
#pragma unroll
      for (int t = 0; t < 4; t++) {
        bf16x8 vb = *(const bf16x8*)&Vts[t * 16 + col][s2 * 32 + quad * 8];
        oacc[0][t] = __builtin_amdgcn_mfma_f32_16x16x32_bf16(pa0, vb, oacc[0][t], 0, 0, 0);
        oacc[1][t] = __builtin_amdgcn_mfma_f32_16x16x32_bf16(pa1, vb, oacc[1][t], 0, 0, 0);
      }
    }
    __syncthreads();
  }

  // epilogue: reduce l across quads, redistribute to C layout, write
#pragma unroll
  for (int s = 0; s < 2; s++) {
    float l = l_lane[s];
    l += __shfl_xor(l, 16);
    l += __shfl_xor(l, 32);
    float inv = 1.0f / l;
#pragma unroll
    for (int r = 0; r < 4; r++) {
      float ir = __shfl(inv, quad * 4 + r);
#pragma unroll
      for (int t = 0; t < 4; t++) {
        obuf[((size_t)bg * NQS + q0 + s * 16 + quad * 4 + r) * DI + h * DHD +
             t * 16 + col] = f2bfh(oacc[s][t][r] * ir);
      }
    }
  }
}

extern "C" void kernel_launch(void* const* d_in, const int* in_sizes, int n_in,
                              void* d_out, int out_size, void* d_ws, size_t ws_size,
                              hipStream_t stream) {
  const float* x = (const float*)d_in[0];
  const float* wqr = (const float*)d_in[1];
  const float* wkvr = (const float*)d_in[2];
  const float* wq = (const float*)d_in[3];
  const float* wkv = (const float*)d_in[4];
  const float* wout = (const float*)d_in[5];
  const float* nullkv = (const float*)d_in[6];
  const float* nulltok = (const float*)d_in[7];
  float* out = (float*)d_out;
  char* ws = (char*)d_ws;
  // workspace layout (bytes)
  float* qlog = (float*)(ws + 0);                  // 256 KB
  float* kvlog = (float*)(ws + 262144);            // 256 KB
  int* qidx = (int*)(ws + 524288);                 // 64 KB
  int* kvidx = (int*)(ws + 589824);                // 32 KB
  float* qscore = (float*)(ws + 622592);           // 64 KB
  float* kvscore = (float*)(ws + 688128);          // 32 KB
  u16* qbuf = (u16*)(ws + 786432);                 // 16 MB  [16][1024][512]
  u16* kbuf = (u16*)(ws + 17563648);               // 8 MB   [16][512][512]
  u16* vtbuf = (u16*)(ws + 25952256);              // 8.13MB [16][8][64][520]
  u16* obuf = (u16*)(ws + 34476032);               // 16 MB  [16][1024][512]
  u16* xbf = (u16*)(ws + 51253248);                // 32 MB  [4][4096][1024]
  u16* wqbf = (u16*)(ws + 84807680);               // 4 MB   [4][512][1024]
  u16* wkvbf = (u16*)(ws + 89001984);              // 8 MB   [4][1024][1024]
  u16* woutbf = (u16*)(ws + 97390592);             // 4 MB   [4][1024][512]
  // dead-region reuse (stream-ordered):
  //  - qpos (256 KB) in qlog's region (qlog dead after topk; qpos_build runs
  //    immediately after topk, before anything reads qpos)
  //  - oproj (32 MiB fp32 [8][1024][1024]) in xbf's region (xbf dead after
  //    gemm_qkvproj; outproj runs after attn)
  int* qpos = (int*)(ws + 0);
  float* oproj = (float*)(ws + 51253248);

  router_kernel<<<4096, 256, 0, stream>>>(x, wqr, wkvr, qlog, kvlog, xbf, wq,
                                          wkv, wout, wqbf, wkvbf, woutbf);
  topk_kernel<<<32, 256, 0, stream>>>(qlog, kvlog, qidx, qscore, kvidx, kvscore);
  qpos_build<<<16, 256, 0, stream>>>(qidx, qpos);
  gemm_qkvproj<<<1024, 256, 0, stream>>>(xbf, qidx, kvidx, wqbf, wkvbf, kvscore,
                                         qbuf, kbuf, vtbuf);
  attn_mfma<<<dim3(8, 8, 16), 256, 0, stream>>>(qbuf, kbuf, vtbuf, nullkv, obuf);
  // batch b in {0,1}: bg 0..7
  gemm_outproj<<<dim3(8, 8, 8), 256, 0, stream>>>(obuf, woutbf, qscore, oproj, 0);
  finalize_gather<<<8192, 256, 0, stream>>>(oproj, qpos, nulltok, out, 0);
  // batch b in {2,3}: bg 8..15
  gemm_outproj<<<dim3(8, 8, 8), 256, 0, stream>>>(obuf, woutbf, qscore, oproj, 8);
  finalize_gather<<<8192, 256, 0, stream>>>(oproj, qpos, nulltok, out, 2);
}

// Round 5
// 330.050 us; speedup vs baseline: 1.4040x; 1.0284x over previous
//
#include <hip/hip_runtime.h>
#include <math.h>

#define NB 4
#define SEQ 4096
#define DM 1024
#define NG 4
#define DI 512
#define NQS 1024
#define NKS 512
#define NHD 8
#define DHD 64
#define VTS 520  // vtbuf row stride (512 cols used, padded)

typedef unsigned int u32;
typedef unsigned short u16;
typedef __bf16 bf16x8 __attribute__((ext_vector_type(8)));
typedef float f32x4 __attribute__((ext_vector_type(4)));

__device__ __forceinline__ float bf2f(u16 u) { return __uint_as_float(((u32)u) << 16); }
__device__ __forceinline__ u16 f2bf(float f) {
  u32 u = __float_as_uint(f);
  u32 r = (u + 0x7FFFu + ((u >> 16) & 1u)) >> 16;
  return (u16)r;
}
// hardware RNE bf16 convert (compiler pairs into v_cvt_pk_bf16_f32)
__device__ __forceinline__ u16 f2bfh(float f) {
  union { __bf16 b; u16 u; } cv;
  cv.b = (__bf16)f;
  return cv.u;
}

// ---------------- router + full bf16 conversion (x read exactly once) ----------------
// No LDS (router weights are 32 KB shared by all blocks -> L1/L2 resident);
// occupancy rises 5 -> 8 blocks/CU. Weight conversion grid-strided in.
__global__ __launch_bounds__(256) void router_kernel(
    const float* __restrict__ x, const float* __restrict__ wqr,
    const float* __restrict__ wkvr, float* __restrict__ qlog,
    float* __restrict__ kvlog, u16* __restrict__ xbf,
    const float* __restrict__ wq, const float* __restrict__ wkv,
    const float* __restrict__ wout, u16* __restrict__ wqbf,
    u16* __restrict__ wkvbf, u16* __restrict__ woutbf) {
  int tid = threadIdx.x;
  // weight conversion: 2,097,152 float4 total over 4096 blocks = 512/block
#pragma unroll
  for (int j = 0; j < 2; j++) {
    int idx = blockIdx.x * 512 + j * 256 + tid;
    const float* src; u16* dst; int off;
    if (idx < 524288)        { src = wq;   dst = wqbf;   off = idx; }
    else if (idx < 1572864)  { src = wkv;  dst = wkvbf;  off = idx - 524288; }
    else                     { src = wout; dst = woutbf; off = idx - 1572864; }
    float4 v = ((const float4*)src)[off];
    ushort4 o;
    o.x = f2bf(v.x); o.y = f2bf(v.y); o.z = f2bf(v.z); o.w = f2bf(v.w);
    ((ushort4*)dst)[off] = o;
  }

  int widx = blockIdx.x * 4 + (tid >> 6);
  int lane = tid & 63;
  int b = widx >> 12, tok = widx & 4095;
  const float4* xr = (const float4*)(x + ((size_t)(b * SEQ + tok)) * DM);
  float4 xv[4];
#pragma unroll
  for (int i = 0; i < 4; i++) xv[i] = xr[i * 64 + lane];
  // emit bf16 row (coalesced: consecutive lanes -> consecutive ushort4)
  ushort4* xrow = (ushort4*)(xbf + ((size_t)(b * SEQ + tok)) * DM);
#pragma unroll
  for (int i = 0; i < 4; i++) {
    ushort4 o;
    o.x = f2bf(xv[i].x); o.y = f2bf(xv[i].y);
    o.z = f2bf(xv[i].z); o.w = f2bf(xv[i].w);
    xrow[i * 64 + lane] = o;
  }
  float accs[8];
#pragma unroll
  for (int r = 0; r < 8; r++) {
    const float4* wr =
        (const float4*)(r < 4 ? wqr + (r << 10) : wkvr + ((r - 4) << 10));
    float a = 0.f;
#pragma unroll
    for (int i = 0; i < 4; i++) {
      float4 w4 = wr[i * 64 + lane];
      a += xv[i].x * w4.x + xv[i].y * w4.y + xv[i].z * w4.z + xv[i].w * w4.w;
    }
    accs[r] = a;
  }
#pragma unroll
  for (int r = 0; r < 8; r++) {
    float a = accs[r];
#pragma unroll
    for (int off = 32; off >= 1; off >>= 1) a += __shfl_xor(a, off);
    if (lane == 0) {
      if (r < 4) qlog[((b << 2) | r) * SEQ + tok] = a;
      else kvlog[((b << 2) | (r - 4)) * SEQ + tok] = a;
    }
  }
}

// ---------------- merged top-k radix select + qpos build ----------------
// blocks 0-15: q (K=1024) + writes qpos (token->position, -1 absent);
// blocks 16-31: kv (K=512). Scores recomputed by exact bit-inversion of the
// radix key (bit-identical to reading L[e]), so qpos may safely overwrite the
// qlog region this block has already consumed into LDS.
__global__ __launch_bounds__(256) void topk_kernel(
    const float* __restrict__ qlog, const float* __restrict__ kvlog,
    int* __restrict__ qidx, float* __restrict__ qscore,
    int* __restrict__ kvidx, float* __restrict__ kvscore,
    int* __restrict__ qpos) {
  __shared__ u32 keys[4096];
  __shared__ int eqlist[2048];
  __shared__ int scnt[4];
  __shared__ int s_gt, s_eq;
  int which = blockIdx.x >> 4;
  int bg = blockIdx.x & 15;
  int K = (which == 0) ? NQS : NKS;
  const float* L = ((which == 0) ? qlog : kvlog) + bg * 4096;
  int* out_idx = ((which == 0) ? qidx : kvidx) + bg * K;
  float* out_score = ((which == 0) ? qscore : kvscore) + bg * K;
  int* qposb = qpos + bg * 4096;
  int tid = threadIdx.x;
  // load keys; same-thread partition then overwrites the region with -1
  for (int e = tid; e < 4096; e += 256) {
    u32 u = __float_as_uint(L[e]);
    keys[e] = (u >> 31) ? ~u : (u | 0x80000000u);
  }
  if (which == 0)
    for (int e = tid; e < 4096; e += 256) qposb[e] = -1;
  if (tid == 0) { s_gt = 0; s_eq = 0; }
  __syncthreads();
  u32 prefix = 0;
  int remaining = K;
  for (int bit = 31; bit >= 0; --bit) {
    u32 want = prefix | (1u << bit);
    u32 mask = ~((1u << bit) - 1u);
    int c = 0;
    for (int e = tid; e < 4096; e += 256) c += ((keys[e] & mask) == want) ? 1 : 0;
#pragma unroll
    for (int off = 32; off >= 1; off >>= 1) c += __shfl_xor(c, off);
    if ((tid & 63) == 0) scnt[tid >> 6] = c;
    __syncthreads();
    int total = scnt[0] + scnt[1] + scnt[2] + scnt[3];
    if (total >= remaining) prefix = want;
    else remaining -= total;
    __syncthreads();
  }
  u32 T = prefix;
  for (int e = tid; e < 4096; e += 256) {
    u32 k = keys[e];
    if (k > T) {
      int pos = atomicAdd(&s_gt, 1);
      out_idx[pos] = e;
      u32 uo = (k >> 31) ? (k & 0x7FFFFFFFu) : ~k;  // invert radix key -> bits of L[e]
      float v = __uint_as_float(uo);
      out_score[pos] = 1.0f / (1.0f + __expf(-v));
      if (which == 0) qposb[e] = pos;
    } else if (k == T) {
      int p = atomicAdd(&s_eq, 1);
      if (p < 2048) eqlist[p] = e;
    }
  }
  __syncthreads();
  int gt = s_gt;
  int eq = min(s_eq, 2048);
  int need = K - gt;
  for (int i = tid; i < eq; i += 256) {
    int my = eqlist[i];
    int rank = 0;
    for (int j = 0; j < eq; j++) rank += (eqlist[j] < my) ? 1 : 0;
    if (rank < need) {
      int pos = gt + rank;
      out_idx[pos] = my;
      u32 k2 = keys[my];
      u32 uo = (k2 >> 31) ? (k2 & 0x7FFFFFFFu) : ~k2;
      float v = __uint_as_float(uo);
      out_score[pos] = 1.0f / (1.0f + __expf(-v));
      if (which == 0) qposb[my] = pos;
    }
  }
}

// ---------------- shared MFMA GEMM core: 128x128 tile, BK=64, swizzled LDS ----------------
struct Ptr4 { const u16* p[4]; };

__device__ __forceinline__ void mfma_core(Ptr4 A, Ptr4 B, u16* Asm, u16* Bsm,
                                          int ktiles, int tid, f32x4 (&acc)[4][4]) {
  int w = tid >> 6, lane = tid & 63;
  int col = lane & 15, quad = lane >> 4;
  int wr = w >> 1, wc = w & 1;
  for (int kt = 0; kt < ktiles; kt++) {
#pragma unroll
    for (int r = 0; r < 4; r++) {
      char* ldsA = (char*)Asm + (r * 256 + w * 64) * 16;
      __builtin_amdgcn_global_load_lds(
          (const __attribute__((address_space(1))) void*)(A.p[r] + kt * 64),
          (__attribute__((address_space(3))) void*)ldsA, 16, 0, 0);
    }
#pragma unroll
    for (int r = 0; r < 4; r++) {
      char* ldsB = (char*)Bsm + (r * 256 + w * 64) * 16;
      __builtin_amdgcn_global_load_lds(
          (const __attribute__((address_space(1))) void*)(B.p[r] + kt * 64),
          (__attribute__((address_space(3))) void*)ldsB, 16, 0, 0);
    }
    __syncthreads();
#pragma unroll
    for (int k04 = 0; k04 < 8; k04 += 4) {
      bf16x8 af[4], bfr[4];
#pragma unroll
      for (int t = 0; t < 4; t++) {
        int rowa = wr * 64 + t * 16 + col;
        int sp = (quad + k04) ^ (col & 7);
        af[t] = *(const bf16x8*)((const char*)Asm + (rowa * 8 + sp) * 16);
        int rowb = wc * 64 + t * 16 + col;
        bfr[t] = *(const bf16x8*)((const char*)Bsm + (rowb * 8 + sp) * 16);
      }
#pragma unroll
      for (int t = 0; t < 4; t++)
#pragma unroll
        for (int u = 0; u < 4; u++)
          acc[t][u] = __builtin_amdgcn_mfma_f32_16x16x32_bf16(af[t], bfr[u], acc[t][u], 0, 0, 0);
    }
    __syncthreads();
  }
}

// ---------------- fused q+kv projection (even/odd interleave — round-3 proven) ----------------
// even blocks: qbuf[bg][1024][512] = gather(xbf) @ wq^T  (pre-scaled by DH^-0.5)
// odd  blocks: kbuf / vtbuf(scaled V^T) = gather(xbf) @ wkv^T
__global__ __launch_bounds__(256) void gemm_qkvproj(
    const u16* __restrict__ xbf, const int* __restrict__ qidx,
    const int* __restrict__ kvidx, const u16* __restrict__ wqbf,
    const u16* __restrict__ wkvbf, const float* __restrict__ kvscore,
    u16* __restrict__ qbuf, u16* __restrict__ kbuf, u16* __restrict__ vtbuf) {
  __shared__ __align__(16) u16 Asm[8192], Bsm[8192];
  __shared__ int ridx[128];
  int tid = threadIdx.x;
  int id = blockIdx.x;
  bool is_q = (id & 1) == 0;
  int sid = id >> 1;                 // 0..511 either way
  int bg = sid >> 5, r5 = sid & 31;
  int b = bg >> 2, g = bg & 3;
  int w = tid >> 6, lane = tid & 63;
  int col = lane & 15, quad = lane >> 4;
  int wr = w >> 1, wc = w & 1;

  if (is_q) {
    int col0 = (r5 & 3) * 128, row0 = (r5 >> 2) * 128;
    if (tid < 128) ridx[tid] = qidx[bg * NQS + row0 + tid];
    __syncthreads();
    Ptr4 A, B;
#pragma unroll
    for (int r = 0; r < 4; r++) {
      int G = r * 256 + tid;
      int row = G >> 3;
      int seg = (G & 7) ^ (row & 7);
      A.p[r] = xbf + ((size_t)b * SEQ + ridx[row]) * DM + seg * 8;
      B.p[r] = wqbf + ((size_t)g * DI + col0 + row) * DM + seg * 8;
    }
    f32x4 acc[4][4] = {};
    mfma_core(A, B, Asm, Bsm, DM / 64, tid, acc);
#pragma unroll
    for (int t = 0; t < 4; t++)
#pragma unroll
      for (int u = 0; u < 4; u++)
#pragma unroll
        for (int r = 0; r < 4; r++) {
          int rowg = row0 + wr * 64 + t * 16 + quad * 4 + r;
          int colg = col0 + wc * 64 + u * 16 + col;
          // pre-scale q by DH^-0.5 = 0.125 (power of two: exact in bf16)
          qbuf[((size_t)bg * NQS + rowg) * DI + colg] = f2bf(acc[t][u][r] * 0.125f);
        }
  } else {
    int col0 = (r5 & 7) * 128, row0 = (r5 >> 3) * 128;
    if (tid < 128) ridx[tid] = kvidx[bg * NKS + row0 + tid];
    __syncthreads();
    Ptr4 A, B;
#pragma unroll
    for (int r = 0; r < 4; r++) {
      int G = r * 256 + tid;
      int row = G >> 3;
      int seg = (G & 7) ^ (row & 7);
      A.p[r] = xbf + ((size_t)b * SEQ + ridx[row]) * DM + seg * 8;
      B.p[r] = wkvbf + ((size_t)g * (2 * DI) + col0 + row) * DM + seg * 8;
    }
    f32x4 acc[4][4] = {};
    mfma_core(A, B, Asm, Bsm, DM / 64, tid, acc);
    if (col0 < DI) {
#pragma unroll
      for (int t = 0; t < 4; t++)
#pragma unroll
        for (int u = 0; u < 4; u++)
#pragma unroll
          for (int r = 0; r < 4; r++) {
            int rowg = row0 + wr * 64 + t * 16 + quad * 4 + r;
            int colg = col0 + wc * 64 + u * 16 + col;
            kbuf[((size_t)bg * NKS + rowg) * DI + colg] = f2bf(acc[t][u][r]);
          }
    } else {
#pragma unroll
      for (int t = 0; t < 4; t++)
#pragma unroll
        for (int r = 0; r < 4; r++) {
          int rowg = row0 + wr * 64 + t * 16 + quad * 4 + r;
          float sc = kvscore[bg * NKS + rowg];
#pragma unroll
          for (int u = 0; u < 4; u++) {
            int vc = col0 - DI + wc * 64 + u * 16 + col;  // 0..511
            int h = vc >> 6, d = vc & 63;
            vtbuf[(((size_t)bg * NHD + h) * DHD + d) * VTS + rowg] =
                f2bf(acc[t][u][r] * sc);
          }
        }
    }
  }
}

// ---------------- out projection: single launch over all 16 bg, split oproj ----------------
__global__ __launch_bounds__(256) void gemm_outproj(
    const u16* __restrict__ obuf, const u16* __restrict__ woutbf,
    const float* __restrict__ qscore, float* __restrict__ oproj_lo,
    float* __restrict__ oproj_hi) {
  int bg = blockIdx.z, g = bg & 3;
  int row0 = blockIdx.y * 128, col0 = blockIdx.x * 128;
  __shared__ __align__(16) u16 Asm[8192], Bsm[8192];
  int tid = threadIdx.x;
  Ptr4 A, B;
#pragma unroll
  for (int r = 0; r < 4; r++) {
    int G = r * 256 + tid;
    int row = G >> 3;
    int seg = (G & 7) ^ (row & 7);
    A.p[r] = obuf + ((size_t)bg * NQS + row0 + row) * DI + seg * 8;
    B.p[r] = woutbf + ((size_t)g * DM + col0 + row) * DI + seg * 8;
  }
  f32x4 acc[4][4] = {};
  mfma_core(A, B, Asm, Bsm, DI / 64, tid, acc);
  int w = tid >> 6, lane = tid & 63;
  int col = lane & 15, quad = lane >> 4;
  int wr = w >> 1, wc = w & 1;
  float* obase = (bg < 8 ? oproj_lo : oproj_hi) + (size_t)(bg & 7) * NQS * DM;
#pragma unroll
  for (int t = 0; t < 4; t++)
#pragma unroll
    for (int r = 0; r < 4; r++) {
      int rowg = row0 + wr * 64 + t * 16 + quad * 4 + r;
      float sc = qscore[bg * NQS + rowg];
      float* orow = obase + (size_t)rowg * DM;
#pragma unroll
      for (int u = 0; u < 4; u++) {
        int colg = col0 + wc * 64 + u * 16 + col;
        orow[colg] = acc[t][u][r] * sc;
      }
    }
}

// ---------------- finalize: gather <=4 group rows, mean, null-token fill ----------------
__global__ __launch_bounds__(256) void finalize_gather(
    const float* __restrict__ oproj_lo, const float* __restrict__ oproj_hi,
    const int* __restrict__ qpos, const float* __restrict__ null_token,
    float* __restrict__ dout) {
  int blk = blockIdx.x;            // 0..16383 (4 b-values x 4096 tokens)
  int b = blk >> 12;
  int tok = blk & 4095;
  int tid = threadIdx.x;
  const float* obase = (b < 2) ? oproj_lo : oproj_hi;
  int zoff = (b & 1) * 4;
  float4 acc = {0.f, 0.f, 0.f, 0.f};
  int cnt = 0;
#pragma unroll
  for (int g = 0; g < 4; g++) {
    int pos = qpos[(((b << 2) | g)) * 4096 + tok];  // block-uniform
    if (pos >= 0) {
      const float4* row =
          (const float4*)(obase + ((size_t)(zoff + g) * NQS + pos) * DM);
      float4 v = row[tid];
      acc.x += v.x; acc.y += v.y; acc.z += v.z; acc.w += v.w;
      cnt++;
    }
  }
  float4* dst = (float4*)(dout + ((size_t)b * SEQ + tok) * DM) + tid;
  if (cnt > 0) {
    float inv = 1.0f / cnt;
    acc.x *= inv; acc.y *= inv; acc.z *= inv; acc.w *= inv;
    *dst = acc;
  } else {
    *dst = ((const float4*)null_token)[tid];
  }
}

// ---------------- MFMA flash attention v4 ----------------
// 32 q per wave (128 q per block, grid qt=8): kb/vb register fragments reused
// across two q-subtiles. Swapped QK (mfma(K,Q) -> S^T): per-lane row-max,
// packed b64 Ps stores. Defer-max THR=8 (T13). Null column analytic prologue.
// T14 issue-early/write-late staging. LDS 36.9 KB -> 4 blocks/CU.
__global__ __launch_bounds__(256, 4) void attn_mfma(
    const u16* __restrict__ qbuf, const u16* __restrict__ kbuf,
    const u16* __restrict__ vtbuf, const float* __restrict__ null_kv,
    u16* __restrict__ obuf) {
  int qt = blockIdx.x;        // 0..7
  int h = blockIdx.y;         // 0..7
  int bg = blockIdx.z;        // 0..15
  int g = bg & 3;
  int tid = threadIdx.x;
  int w = tid >> 6, lane = tid & 63;
  int col = lane & 15, quad = lane >> 4;

  __shared__ __align__(16) u16 Ks[64][72];
  __shared__ __align__(16) u16 Vts[64][72];
  __shared__ __align__(16) u16 Ps[4][32][72];

  int q0 = qt * 128 + w * 32;
  const u16* qp0 = qbuf + ((size_t)bg * NQS + q0 + col) * DI + h * DHD + quad * 8;
  bf16x8 qa[2][2];
  qa[0][0] = *(const bf16x8*)qp0;
  qa[0][1] = *(const bf16x8*)(qp0 + 32);
  qa[1][0] = *(const bf16x8*)(qp0 + 16 * DI);
  qa[1][1] = *(const bf16x8*)(qp0 + 16 * DI + 32);

  // --- null-column prologue: exact online-softmax init (per-lane q = col) ---
  const float* kn = null_kv + ((size_t)(0 * NG + g) * NHD + h) * DHD;
  const float* vn = null_kv + ((size_t)(1 * NG + g) * NHD + h) * DHD;
  float m_run[2], l_lane[2];
  f32x4 oacc[2][4];
#pragma unroll
  for (int s = 0; s < 2; s++) {
    float sn = 0.f;
#pragma unroll
    for (int i = 0; i < 8; i++) {
      sn += (float)qa[s][0][i] * kn[quad * 8 + i];
      sn += (float)qa[s][1][i] * kn[32 + quad * 8 + i];
    }
    sn += __shfl_xor(sn, 16);
    sn += __shfl_xor(sn, 32);
    m_run[s] = sn;                       // running max = s_null, p_null = 1
    l_lane[s] = (quad == 0) ? 1.f : 0.f; // null's contribution, seeded once
  }
#pragma unroll
  for (int t = 0; t < 4; t++) {
    float v = vn[t * 16 + col];          // oacc0 = 1 * v_null (all q rows)
    f32x4 tmp = {v, v, v, v};
    oacc[0][t] = tmp;
    oacc[1][t] = tmp;
  }

  // --- staging: 64x64 K tile + 64x64 V^T tile, 32B per thread each ---
  int sr = tid >> 2, ss = tid & 3;
  const u16* kptr = kbuf + ((size_t)bg * NKS + sr) * DI + h * DHD + ss * 16;
  const u16* vptr = vtbuf + (((size_t)bg * NHD + h) * DHD + sr) * VTS + ss * 16;
  uint4* kdst = (uint4*)&Ks[sr][ss * 16];
  uint4* vdst = (uint4*)&Vts[sr][ss * 16];
  uint4 ck0, ck1, cv0, cv1;
  { const uint4* p = (const uint4*)kptr; ck0 = p[0]; ck1 = p[1]; }
  { const uint4* p = (const uint4*)vptr; cv0 = p[0]; cv1 = p[1]; }

  for (int c = 0; c < 8; ++c) {
    // write-late: regs (loaded last iteration) -> LDS; then issue-early next
    kdst[0] = ck0; kdst[1] = ck1;
    vdst[0] = cv0; vdst[1] = cv1;
    if (c < 7) {
      const uint4* p = (const uint4*)(kptr + (size_t)(c + 1) * 64 * DI);
      ck0 = p[0]; ck1 = p[1];
      const uint4* q4 = (const uint4*)(vptr + (c + 1) * 64);
      cv0 = q4[0]; cv1 = q4[1];
    }
    __syncthreads();

    // QK^T swapped: sv[s][t] rows = k (quad*4+r within 16-tile t), col = q
    f32x4 sv[2][4];
#pragma unroll
    for (int t = 0; t < 4; t++) {
      bf16x8 kb0 = *(const bf16x8*)&Ks[t * 16 + col][quad * 8];
      bf16x8 kb1 = *(const bf16x8*)&Ks[t * 16 + col][quad * 8 + 32];
      f32x4 z = {0.f, 0.f, 0.f, 0.f};
      f32x4 s0 = __builtin_amdgcn_mfma_f32_16x16x32_bf16(kb0, qa[0][0], z, 0, 0, 0);
      sv[0][t] = __builtin_amdgcn_mfma_f32_16x16x32_bf16(kb1, qa[0][1], s0, 0, 0, 0);
      f32x4 s1 = __builtin_amdgcn_mfma_f32_16x16x32_bf16(kb0, qa[1][0], z, 0, 0, 0);
      sv[1][t] = __builtin_amdgcn_mfma_f32_16x16x32_bf16(kb1, qa[1][1], s1, 0, 0, 0);
    }

    // softmax per q-subtile (per-lane: one q = col, 16 k-values in-register)
#pragma unroll
    for (int s = 0; s < 2; s++) {
      float pm = sv[s][0][0];
#pragma unroll
      for (int t = 0; t < 4; t++)
#pragma unroll
        for (int r = 0; r < 4; r++) pm = fmaxf(pm, sv[s][t][r]);
      pm = fmaxf(pm, __shfl_xor(pm, 16));
      pm = fmaxf(pm, __shfl_xor(pm, 32));
      if (!__all(pm <= m_run[s] + 8.0f)) {   // T13 defer-max
        float mnew = fmaxf(m_run[s], pm);
        float alpha = __expf(m_run[s] - mnew);
        m_run[s] = mnew;
        l_lane[s] *= alpha;
#pragma unroll
        for (int r = 0; r < 4; r++) {
          float a_o = __shfl(alpha, quad * 4 + r);
#pragma unroll
          for (int t = 0; t < 4; t++) oacc[s][t][r] *= a_o;
        }
      }
      float rs = 0.f;
#pragma unroll
      for (int t = 0; t < 4; t++) {
        float p0 = __expf(sv[s][t][0] - m_run[s]);
        float p1 = __expf(sv[s][t][1] - m_run[s]);
        float p2 = __expf(sv[s][t][2] - m_run[s]);
        float p3 = __expf(sv[s][t][3] - m_run[s]);
        rs += (p0 + p1) + (p2 + p3);
        u32 lo = (u32)f2bfh(p0) | ((u32)f2bfh(p1) << 16);
        u32 hi = (u32)f2bfh(p2) | ((u32)f2bfh(p3) << 16);
        // 4 consecutive k per lane -> one b64 store
        *(uint2*)&Ps[w][s * 16 + col][t * 16 + quad * 4] = make_uint2(lo, hi);
      }
      l_lane[s] += rs;
    }

    // PV: vb fragments reused for both q-subtiles
#pragma unroll
    for (int s2 = 0; s2 < 2; s2++) {
      bf16x8 pa0 = *(const bf16x8*)&Ps[w][col][s2 * 32 + quad * 8];
      bf16x8 pa1 = *(const bf16x8*)&Ps[w][16 + col][s2 * 32 + quad * 8];
#pragma unroll
      for (int t = 0; t < 4; t++) {
        bf16x8 vb = *(const bf16x8*)&Vts[t * 16 + col][s2 * 32 + quad * 8];
        oacc[0][t] = __builtin_amdgcn_mfma_f32_16x16x32_bf16(pa0, vb, oacc[0][t], 0, 0, 0);
        oacc[1][t] = __builtin_amdgcn_mfma_f32_16x16x32_bf16(pa1, vb, oacc[1][t], 0, 0, 0);
      }
    }
    __syncthreads();
  }

  // epilogue: reduce l across quads, redistribute to C layout, write
#pragma unroll
  for (int s = 0; s < 2; s++) {
    float l = l_lane[s];
    l += __shfl_xor(l, 16);
    l += __shfl_xor(l, 32);
    float inv = 1.0f / l;
#pragma unroll
    for (int r = 0; r < 4; r++) {
      float ir = __shfl(inv, quad * 4 + r);
#pragma unroll
      for (int t = 0; t < 4; t++) {
        obuf[((size_t)bg * NQS + q0 + s * 16 + quad * 4 + r) * DI + h * DHD +
             t * 16 + col] = f2bfh(oacc[s][t][r] * ir);
      }
    }
  }
}

extern "C" void kernel_launch(void* const* d_in, const int* in_sizes, int n_in,
                              void* d_out, int out_size, void* d_ws, size_t ws_size,
                              hipStream_t stream) {
  const float* x = (const float*)d_in[0];
  const float* wqr = (const float*)d_in[1];
  const float* wkvr = (const float*)d_in[2];
  const float* wq = (const float*)d_in[3];
  const float* wkv = (const float*)d_in[4];
  const float* wout = (const float*)d_in[5];
  const float* nullkv = (const float*)d_in[6];
  const float* nulltok = (const float*)d_in[7];
  float* out = (float*)d_out;
  char* ws = (char*)d_ws;
  // workspace layout (bytes)
  float* qlog = (float*)(ws + 0);                  // 256 KB
  float* kvlog = (float*)(ws + 262144);            // 256 KB
  int* qidx = (int*)(ws + 524288);                 // 64 KB
  int* kvidx = (int*)(ws + 589824);                // 32 KB
  float* qscore = (float*)(ws + 622592);           // 64 KB
  float* kvscore = (float*)(ws + 688128);          // 32 KB
  u16* qbuf = (u16*)(ws + 786432);                 // 16 MB  [16][1024][512]
  u16* kbuf = (u16*)(ws + 17563648);               // 8 MB   [16][512][512]
  u16* vtbuf = (u16*)(ws + 25952256);              // 8.13MB [16][8][64][520]
  u16* obuf = (u16*)(ws + 34476032);               // 16 MB  [16][1024][512]
  u16* xbf = (u16*)(ws + 51253248);                // 32 MB  [4][4096][1024]
  u16* wqbf = (u16*)(ws + 84807680);               // 4 MB   [4][512][1024]
  u16* wkvbf = (u16*)(ws + 89001984);              // 8 MB   [4][1024][1024]
  u16* woutbf = (u16*)(ws + 97390592);             // 4 MB   [4][1024][512]
  // dead-region reuse (stream-ordered):
  //  - qpos (256 KB) in qlog's region, written directly by topk (which has
  //    already consumed qlog into LDS; same-thread partition -> no race)
  //  - oproj_lo (32 MB fp32, bg 0..7)  in qbuf+kbuf+vtbuf region (dead after attn)
  //  - oproj_hi (32 MB fp32, bg 8..15) in xbf region (dead after qkvproj)
  int* qpos = (int*)(ws + 0);
  float* oproj_lo = (float*)(ws + 786432);
  float* oproj_hi = (float*)(ws + 51253248);

  router_kernel<<<4096, 256, 0, stream>>>(x, wqr, wkvr, qlog, kvlog, xbf, wq,
                                          wkv, wout, wqbf, wkvbf, woutbf);
  topk_kernel<<<32, 256, 0, stream>>>(qlog, kvlog, qidx, qscore, kvidx, kvscore,
                                      qpos);
  gemm_qkvproj<<<1024, 256, 0, stream>>>(xbf, qidx, kvidx, wqbf, wkvbf, kvscore,
                                         qbuf, kbuf, vtbuf);
  attn_mfma<<<dim3(8, 8, 16), 256, 0, stream>>>(qbuf, kbuf, vtbuf, nullkv, obuf);
  gemm_outproj<<<dim3(8, 8, 16), 256, 0, stream>>>(obuf, woutbf, qscore,
                                                   oproj_lo, oproj_hi);
  finalize_gather<<<16384, 256, 0, stream>>>(oproj_lo, oproj_hi, qpos, nulltok,
                                             out);
}